// Round 4
// baseline (202.603 us; speedup 1.0000x reference)
//
#include <hip/hip_runtime.h>
#include <hip/hip_bf16.h>

#define B_    8
#define CIN   256
#define COUT  768
#define G_    24
#define PW    40         // padded row width (16B-aligned rows)
#define PLANE 1440       // 40*36
#define EPS_  1e-5f

typedef float f32x4 __attribute__((ext_vector_type(4)));
typedef short s16x8 __attribute__((ext_vector_type(8)));
typedef unsigned short ushort_t;
typedef unsigned short u16x4 __attribute__((ext_vector_type(4)));
typedef unsigned long long ull_t;

// LDS-only fence: compiler reordering barrier + s_waitcnt lgkmcnt(0).
// Does NOT wait vmcnt -> global prefetch loads stay in flight.
#define LDS_FENCE() do { asm volatile("" ::: "memory"); \
                         __builtin_amdgcn_s_waitcnt(0xC07F); \
                         asm volatile("" ::: "memory"); } while (0)

static __device__ __forceinline__ ushort_t f2bf(float f) {
    union { float f; unsigned u; } a; a.f = f;
    const unsigned u = a.u;
    const unsigned r = u + 0x7FFFu + ((u >> 16) & 1u);
    return (ushort_t)(r >> 16);
}
static __device__ __forceinline__ float bf2f(ushort_t h) {
    union { unsigned u; float f; } a; a.u = ((unsigned)h) << 16; return a.f;
}
static __device__ __forceinline__ void st4(float* dst, u16x4 v) {
    *(f32x4*)dst = f32x4{ bf2f(v[0]), bf2f(v[1]), bf2f(v[2]), bf2f(v[3]) };
}
static __device__ __forceinline__ unsigned pk2(float lo, float hi) {
    return (unsigned)f2bf(lo) | ((unsigned)f2bf(hi) << 16);
}

// ---------------- Kernel 0: one-time prep --------------------------------
// blocks 0..511 : transpose+convert x[b][k][n] fp32 -> xT[b][n][k] bf16
//                 (64x64 tiles via LDS; read and write both coalesced)
// blocks 512+   : convert conv_w fp32 -> bf16 (layout unchanged [m][k])
__launch_bounds__(256)
__global__ void prep(const float* __restrict__ x, const float* __restrict__ wsrc,
                     ushort_t* __restrict__ xT, ushort_t* __restrict__ wbf) {
    const int bid = blockIdx.x;
    const int t = threadIdx.x;
    if (bid < 512) {
        const int nt = bid & 15, kt = (bid >> 4) & 3, b = bid >> 6;
        const int n0 = nt * 64, k0 = kt * 64;
        __shared__ float Ts[64][65];     // +1 pad: column reads 2-way free
        const int kr = t >> 2, c4 = t & 3;
        const float* src = x + (size_t)b * (CIN * 1024) + (size_t)(k0 + kr) * 1024 + n0 + c4 * 16;
        const float4 v0 = *(const float4*)(src + 0);
        const float4 v1 = *(const float4*)(src + 4);
        const float4 v2 = *(const float4*)(src + 8);
        const float4 v3 = *(const float4*)(src + 12);
        float* d = &Ts[kr][c4 * 16];
        *(float4*)(d + 0) = v0; *(float4*)(d + 4) = v1;
        *(float4*)(d + 8) = v2; *(float4*)(d + 12) = v3;
        __syncthreads();
        const int nr = t >> 2, k4 = t & 3;
        unsigned pk[8];
        #pragma unroll
        for (int i = 0; i < 8; ++i)
            pk[i] = pk2(Ts[k4 * 16 + 2 * i][nr], Ts[k4 * 16 + 2 * i + 1][nr]);
        ushort_t* dst = xT + (size_t)b * (1024 * 256) + (size_t)(n0 + nr) * 256 + k0 + k4 * 16;
        *(uint4*)(dst + 0) = uint4{ pk[0], pk[1], pk[2], pk[3] };
        *(uint4*)(dst + 8) = uint4{ pk[4], pk[5], pk[6], pk[7] };
    } else {
        const int wid = bid - 512;       // 96 blocks x 2048 elems
        const size_t idx = (size_t)wid * 2048 + (size_t)t * 8;
        const float4 u0 = *(const float4*)(wsrc + idx);
        const float4 u1 = *(const float4*)(wsrc + idx + 4);
        uint4 o;
        o.x = pk2(u0.x, u0.y); o.y = pk2(u0.z, u0.w);
        o.z = pk2(u1.x, u1.y); o.w = pk2(u1.z, u1.w);
        *(uint4*)(wbf + idx) = o;
    }
}

// ---------------- Kernel 1: bf16 MFMA GEMM -> attn + rowAgg ------------------
__launch_bounds__(256)
__global__ void conv_gemm(const ushort_t* __restrict__ wbf, const ushort_t* __restrict__ xT,
                          const float* __restrict__ bias, ushort_t* __restrict__ attn,
                          float* __restrict__ rowAgg) {
    const int t = threadIdx.x;
    const int wv = t >> 6, lane = t & 63;
    const int q = lane >> 4, l15 = lane & 15;
    const int m0 = blockIdx.y * 64;
    const int mw = wv * 16;
    const int n_t = blockIdx.x * 64;
    const int b = n_t >> 10, nl0 = n_t & 1023;
    const int y0 = nl0 >> 5;

    __shared__ ushort_t Bs[64][264];     // [n][k] bf16, row stride 264 hw (33792 B)
    ushort_t (*Ct)[2][44] = (ushort_t (*)[2][44])(&Bs[0][0]);
    float (*red)[11]      = (float (*)[11])((char*)(&Bs[0][0]) + 64 * 2 * 44 * 2);

    // ---- stage B: xT[b][nl0+row][0..255] bf16 -> Bs[row][k] (straight copy)
    {
        const ushort_t* src = xT + (size_t)b * (1024 * 256) + (size_t)nl0 * 256;
        #pragma unroll
        for (int i = 0; i < 8; ++i) {
            const int id = i * 256 + t;
            const int row = id >> 5, seg = id & 31;
            *(s16x8*)&Bs[row][seg * 8] = *(const s16x8*)(src + row * 256 + seg * 8);
        }
    }
    __syncthreads();

    const ushort_t* aPf = wbf + (size_t)(m0 + mw + l15) * 256 + q * 8;

    f32x4 acc[4] = {{0,0,0,0},{0,0,0,0},{0,0,0,0},{0,0,0,0}};
    #pragma unroll
    for (int k0 = 0; k0 < 256; k0 += 32) {
        const s16x8 a = *(const s16x8*)(aPf + k0);
        const int kk = k0 + q * 8;
        const s16x8 b0 = *(const s16x8*)&Bs[l15 +  0][kk];
        const s16x8 b1 = *(const s16x8*)&Bs[l15 + 16][kk];
        const s16x8 b2 = *(const s16x8*)&Bs[l15 + 32][kk];
        const s16x8 b3 = *(const s16x8*)&Bs[l15 + 48][kk];
        acc[0] = __builtin_amdgcn_mfma_f32_16x16x32_bf16(a, b0, acc[0], 0, 0, 0);
        acc[1] = __builtin_amdgcn_mfma_f32_16x16x32_bf16(a, b1, acc[1], 0, 0, 0);
        acc[2] = __builtin_amdgcn_mfma_f32_16x16x32_bf16(a, b2, acc[2], 0, 0, 0);
        acc[3] = __builtin_amdgcn_mfma_f32_16x16x32_bf16(a, b3, acc[3], 0, 0, 0);
    }
    __syncthreads();   // Bs dead; Ct/red aliasing begins

    float bb[4];
    #pragma unroll
    for (int r = 0; r < 4; ++r) bb[r] = bias[m0 + mw + q * 4 + r];
    #pragma unroll
    for (int j = 0; j < 4; ++j) {
        const int yy = j >> 1, xx = (j & 1) * 16 + l15;
        #pragma unroll
        for (int r = 0; r < 4; ++r)
            Ct[mw + q * 4 + r][yy][2 + xx] = f2bf(acc[j][r] + bb[r]);
    }
    #pragma unroll
    for (int it = 0; it < 2; ++it) {
        const int id = it * 256 + t;
        const int m = id >> 3, yy = (id >> 2) & 1, pos = id & 3;
        const int us = (pos == 0) ? 0 : (32 + 2 * pos);
        *(unsigned*)&Ct[m][yy][us] = 0u;
    }
    __syncthreads();

    ushort_t* pb = attn + ((size_t)(b * COUT + m0)) * PLANE;
    #pragma unroll
    for (int it = 0; it < 5; ++it) {
        const int id = it * 256 + t;
        const int m = id / 20, rem = id % 20, yy = rem / 10, s = rem % 10;
        const ull_t v = *(const ull_t*)&Ct[m][yy][s * 4];
        *(ull_t*)(pb + (size_t)m * PLANE + (y0 + yy + 2) * PW + s * 4) = v;
    }
    if (y0 == 0 || y0 == 30) {
        const int rowA = (y0 == 0) ? 0 : 34;
        #pragma unroll
        for (int it = 0; it < 5; ++it) {
            const int id = it * 256 + t;
            const int m = id / 20, rem = id % 20, yy = rem / 10, s = rem % 10;
            *(ull_t*)(pb + (size_t)m * PLANE + (rowA + yy) * PW + s * 4) = 0ull;
        }
    }

    if (t < 128) {
        const int gi = t >> 6, yy = (t >> 5) & 1, c = t & 31;
        const int m = gi * 32 + c;
        float lin = 0.f, sq = 0.f, e0 = 0.f, e1 = 0.f, e30 = 0.f, e31 = 0.f;
        #pragma unroll
        for (int u = 0; u < 9; ++u) {
            const ull_t vv = *(const ull_t*)&Ct[m][yy][u * 4];
            const unsigned lo = (unsigned)vv, hi = (unsigned)(vv >> 32);
            union { unsigned u; float f; } f0, f1, f2, f3;
            f0.u = lo << 16; f1.u = lo & 0xffff0000u;
            f2.u = hi << 16; f3.u = hi & 0xffff0000u;
            lin += (f0.f + f1.f) + (f2.f + f3.f);
            sq  += (f0.f * f0.f + f1.f * f1.f) + (f2.f * f2.f + f3.f * f3.f);
            if (u == 0) { e0 = f2.f; e1 = f3.f; }
            if (u == 8) { e30 = f0.f; e31 = f1.f; }
        }
        red[t][0] = lin; red[t][1] = sq;
        red[t][2] = e0;  red[t][3] = e0 * e0;
        red[t][4] = e1;  red[t][5] = e1 * e1;
        red[t][6] = e30; red[t][7] = e30 * e30;
        red[t][8] = e31; red[t][9] = e31 * e31;
    }
    __syncthreads();
    if (t < 40) {
        const int s = t % 10, gy = t / 10;
        const int gi = gy >> 1, yy = gy & 1;
        float sum = 0.f;
        #pragma unroll
        for (int c = 0; c < 32; ++c) sum += red[gi * 64 + yy * 32 + c][s];
        const int g = blockIdx.y * 2 + gi;
        rowAgg[(((size_t)b * G_ + g) * 32 + (y0 + yy)) * 10 + s] = sum;
    }
}

// ---------------- Kernel 2: local attention — 2-wave blocks, 2-row slabs.
// Deep named-register prefetch rings (QK: 4 planes ahead; PV: up to 7 ahead;
// V0-V7 rotate in through the QK ring tail) + full unroll so ring indices are
// static. XCD-swizzled blockIdx: each XCD covers one full batch image (2.2 MB
// attn slice fits its 4 MB L2), making the 2.67x slab row re-reads local hits.
__launch_bounds__(128)
__global__ void local_attn(const ushort_t* __restrict__ attn,
                           const float* __restrict__ rowAgg,
                           const float* __restrict__ gn_w, const float* __restrict__ gn_b,
                           float* __restrict__ out) {
    const int bx = blockIdx.x;           // 1024 = 8 XCD chunks x 128
    const int wid = (bx & 7) * 128 + (bx >> 3);   // bijective XCD swizzle
    const int b = wid >> 7;
    const int n = (wid >> 4) & 7;
    const int i0 = (wid & 15) * 2;       // first image row of the 2-row slab
    const int t = threadIdx.x;           // 128
    const int h = t >> 6;                // wave index = channel half
    const int lane = t & 63;
    const int r = lane >> 5;             // row within slab
    const int j = lane & 31;             // pixel column

    __shared__ float KB[2][2][240];      // [half][buf][6 rows x 40]
    __shared__ float QB[2][2][240];
    __shared__ float ex[128][27];        // sal exchange, stride-27 conflict-free
    __shared__ float rpL[96][5], rp2L[96][5];
    __shared__ float s_m[75], s_r[75];
    __shared__ float s_rq[25], s_mq[25], s_rk[25], s_ck[25], s_rv[25], s_cv[25];
    __shared__ float s_gw[96], s_gb[96];

    if (t < 96) { s_gw[t] = gn_w[n * 96 + t]; s_gb[t] = gn_b[n * 96 + t]; }

    // ---- fused gnfin, phase 1: per-(group,row) window column sums ----------
    const float* rab = rowAgg + (size_t)((b * G_ + n * 3) * 32) * 10;
    if (t < 96) {
        const float* a = rab + (size_t)t * 10;
        const float S = a[0], Sq = a[1];
        const float e0 = a[2], q0 = a[3], e1 = a[4], q1 = a[5];
        const float e30 = a[6], q30 = a[7], e31 = a[8], q31 = a[9];
        rpL[t][0] = S - e30 - e31; rpL[t][1] = S - e31; rpL[t][2] = S;
        rpL[t][3] = S - e0;        rpL[t][4] = S - e0 - e1;
        rp2L[t][0] = Sq - q30 - q31; rp2L[t][1] = Sq - q31; rp2L[t][2] = Sq;
        rp2L[t][3] = Sq - q0;        rp2L[t][4] = Sq - q0 - q1;
    }
    __syncthreads();

    // ---- fused gnfin, phase 2: 75 (group,window) mean/rstd entries ---------
    if (t < 75) {
        const int gi = t / 25, p = t % 25;
        const int kw = p % 5, kh = p / 5;
        const int rb = gi * 32;
        float cs = 0.f, cs2 = 0.f;
        #pragma unroll
        for (int yy = 0; yy < 32; ++yy) { cs += rpL[rb + yy][kw]; cs2 += rp2L[rb + yy][kw]; }
        if (kh == 0)      { cs -= rpL[rb + 30][kw] + rpL[rb + 31][kw]; cs2 -= rp2L[rb + 30][kw] + rp2L[rb + 31][kw]; }
        else if (kh == 1) { cs -= rpL[rb + 31][kw];                    cs2 -= rp2L[rb + 31][kw]; }
        else if (kh == 3) { cs -= rpL[rb + 0][kw];                     cs2 -= rp2L[rb + 0][kw]; }
        else if (kh == 4) { cs -= rpL[rb + 0][kw] + rpL[rb + 1][kw];   cs2 -= rp2L[rb + 0][kw] + rp2L[rb + 1][kw]; }
        const float inv_n = 1.f / 32768.f;
        const float mean = cs * inv_n;
        const float var  = cs2 * inv_n - mean * mean;
        s_m[t] = mean;
        s_r[t] = rsqrtf(var + EPS_);
    }
    __syncthreads();

    if (t < 25) {
        const float mK = s_m[t],      rK = s_r[t];
        const float mQ = s_m[25 + t], rQ = s_r[25 + t];
        const float mV = s_m[50 + t], rV = s_r[50 + t];
        s_rk[t] = rK; s_ck[t] = mK * rK;
        s_rq[t] = rQ; s_mq[t] = mQ * rQ;
        s_rv[t] = rV; s_cv[t] = mV * rV;
    }
    __syncthreads();

    float rq[25]; float cQ = 0.f;
    #pragma unroll
    for (int p = 0; p < 25; ++p) { rq[p] = s_rq[p]; cQ += s_mq[p]; }

    // wave-private staging: padded rows i0..i0+5 (240 bf16/plane); 60 stagers
    const ushort_t* regB = attn + (size_t)(b * COUT + n * 96) * PLANE + i0 * PW;
    const bool stg = (lane < 60);
    const int eo = lane * 4;
    const int base = r * PW + j;

    const ushort_t* baseK = regB + (size_t)(h * 16) * PLANE;
    const ushort_t* baseQ = regB + (size_t)(32 + h * 16) * PLANE;
    const ushort_t* baseV = regB + (size_t)(64 + h * 16) * PLANE;

    // prefetch ring: k1..k4 / q1..q4 hold planes cur+1..cur+4 (4-iter slack)
    u16x4 k1{0,0,0,0}, k2{0,0,0,0}, k3{0,0,0,0}, k4{0,0,0,0};
    u16x4 q1{0,0,0,0}, q2{0,0,0,0}, q3{0,0,0,0}, q4{0,0,0,0};
    if (stg) {
        const u16x4 c0K = *(const u16x4*)(baseK + eo);
        const u16x4 c0Q = *(const u16x4*)(baseQ + eo);
        st4(&KB[h][0][eo], c0K);
        st4(&QB[h][0][eo], c0Q);
        k1 = *(const u16x4*)(baseK + 1 * (size_t)PLANE + eo);
        q1 = *(const u16x4*)(baseQ + 1 * (size_t)PLANE + eo);
        k2 = *(const u16x4*)(baseK + 2 * (size_t)PLANE + eo);
        q2 = *(const u16x4*)(baseQ + 2 * (size_t)PLANE + eo);
        k3 = *(const u16x4*)(baseK + 3 * (size_t)PLANE + eo);
        q3 = *(const u16x4*)(baseQ + 3 * (size_t)PLANE + eo);
        k4 = *(const u16x4*)(baseK + 4 * (size_t)PLANE + eo);
        q4 = *(const u16x4*)(baseQ + 4 * (size_t)PLANE + eo);
    }
    LDS_FENCE();

    float sal[25];
    #pragma unroll
    for (int p = 0; p < 25; ++p) sal[p] = 0.f;
    float sumQ2 = 0.f, sumQB = 0.f;

    #pragma unroll
    for (int cc = 0; cc < 16; ++cc) {
        const int buf = cc & 1;
        if (stg && cc < 15) {
            st4(&KB[h][buf ^ 1][eo], k1);     // plane cc+1
            st4(&QB[h][buf ^ 1][eo], q1);
            k1 = k2; k2 = k3; k3 = k4;
            q1 = q2; q2 = q3; q3 = q4;
            if (cc < 11) {                    // K/Q planes cc+5
                k4 = *(const u16x4*)(baseK + (size_t)(cc + 5) * PLANE + eo);
                q4 = *(const u16x4*)(baseQ + (size_t)(cc + 5) * PLANE + eo);
            } else {                          // tail: V0..V3 / V4..V7
                k4 = *(const u16x4*)(baseV + (size_t)(cc - 11) * PLANE + eo);
                q4 = *(const u16x4*)(baseV + (size_t)(cc - 7) * PLANE + eo);
            }
        }
        const int ch = h * 16 + cc;
        const float* qb = &QB[h][buf][base];
        const float* kb = &KB[h][buf][base];
        float qa0 = 0.f, qa1 = 0.f, qa2 = 0.f, qa3 = 0.f, qa4 = 0.f;
        #pragma unroll
        for (int kw = 0; kw < 5; ++kw) {
            qa0 += rq[0 * 5 + kw] * qb[0 * PW + kw];
            qa1 += rq[1 * 5 + kw] * qb[1 * PW + kw];
            qa2 += rq[2 * 5 + kw] * qb[2 * PW + kw];
            qa3 += rq[3 * 5 + kw] * qb[3 * PW + kw];
            qa4 += rq[4 * 5 + kw] * qb[4 * PW + kw];
        }
        const float qa = (qa0 + qa1) + (qa2 + qa3) + qa4;
        const float qk  = s_gw[32 + ch] * ((qa - cQ) * 0.04f) + s_gb[32 + ch];
        const float qk2 = qk * s_gw[ch];
        sumQ2 += qk2; sumQB += qk * s_gb[ch];
        #pragma unroll
        for (int kh = 0; kh < 5; ++kh)
            #pragma unroll
            for (int kw = 0; kw < 5; ++kw)
                sal[kh * 5 + kw] += qk2 * kb[kh * PW + kw];
        LDS_FENCE();
    }
    // ring now holds V planes: k1..k4 = V0..V3, q1..q4 = V4..V7

    // cross-wave exchange (lane t <-> t^64): write partials + stage V0, barrier
    #pragma unroll
    for (int p = 0; p < 25; ++p) ex[t][p] = sal[p];
    ex[t][25] = sumQ2; ex[t][26] = sumQB;
    if (stg) st4(&KB[h][0][eo], k1);     // V0 -> buf0 (wave-private)
    __syncthreads();
    const int par = t ^ 64;
    #pragma unroll
    for (int p = 0; p < 25; ++p) sal[p] += ex[par][p];
    sumQ2 += ex[par][25]; sumQB += ex[par][26];

    #pragma unroll
    for (int p = 0; p < 25; ++p) sal[p] = s_rk[p] * sal[p] - s_ck[p] * sumQ2 + sumQB;

    const float scale = 0.17677669529663687f;  // 1/sqrt(32)
    float mmax = -3.4e38f;
    #pragma unroll
    for (int p = 0; p < 25; ++p) { sal[p] *= scale; mmax = fmaxf(mmax, sal[p]); }
    float ssum = 0.f;
    #pragma unroll
    for (int p = 0; p < 25; ++p) { sal[p] = __expf(sal[p] - mmax); ssum += sal[p]; }
    const float rs = 1.f / ssum;
    float cV2 = 0.f;
    #pragma unroll
    for (int p = 0; p < 25; ++p) {
        const float m = sal[p] * rs;
        sal[p] = m * s_rv[p];        // reuse sal as V-tap weights
        cV2 += m * s_cv[p];
    }
    LDS_FENCE();

    // PV ring: k2,k3,k4,q1..q4 = V1..V7; loads at cc=0..7 fetch V8..V15
    #pragma unroll
    for (int cc = 0; cc < 16; ++cc) {
        const int buf = cc & 1;
        if (stg && cc < 15) {
            st4(&KB[h][buf ^ 1][eo], k2);     // V(cc+1)
            k2 = k3; k3 = k4; k4 = q1; q1 = q2; q2 = q3; q3 = q4;
            if (cc < 8)
                q4 = *(const u16x4*)(baseV + (size_t)(cc + 8) * PLANE + eo);
        }
        const int v = h * 16 + cc;
        const float* vb = &KB[h][buf][base];
        float a0 = 0.f, a1 = 0.f, a2 = 0.f, a3 = 0.f, a4 = 0.f;
        #pragma unroll
        for (int kw = 0; kw < 5; ++kw) {
            a0 += sal[0 * 5 + kw] * vb[0 * PW + kw];
            a1 += sal[1 * 5 + kw] * vb[1 * PW + kw];
            a2 += sal[2 * 5 + kw] * vb[2 * PW + kw];
            a3 += sal[3 * 5 + kw] * vb[3 * PW + kw];
            a4 += sal[4 * 5 + kw] * vb[4 * PW + kw];
        }
        const float acc = (a0 + a1) + (a2 + a3) + a4;
        out[((size_t)(b * 256 + n * 32 + v) * 32 + (i0 + r)) * 32 + j] =
            s_gw[64 + v] * acc + (s_gb[64 + v] - s_gw[64 + v] * cV2);
        LDS_FENCE();
    }
}

extern "C" void kernel_launch(void* const* d_in, const int* in_sizes, int n_in,
                              void* d_out, int out_size, void* d_ws, size_t ws_size,
                              hipStream_t stream) {
    const float* x      = (const float*)d_in[0];
    const float* conv_w = (const float*)d_in[1];
    const float* conv_b = (const float*)d_in[2];
    const float* gn_w   = (const float*)d_in[3];
    const float* gn_b   = (const float*)d_in[4];
    float* out = (float*)d_out;

    // ws: attn bf16 padded | rowAgg f32 | xT bf16 | wbf bf16
    ushort_t* attn    = (ushort_t*)d_ws;                    // 8,847,360 ushorts
    float*    rowAgg  = (float*)(attn + 8847360);           // 61,440 floats
    ushort_t* xT      = (ushort_t*)(rowAgg + 61440);        // 2,097,152 ushorts
    ushort_t* wbf     = xT + 2097152;                       // 196,608 ushorts

    prep<<<608, 256, 0, stream>>>(x, conv_w, xT, wbf);
    conv_gemm<<<dim3(128, 12), 256, 0, stream>>>(wbf, xT, conv_b, attn, rowAgg);
    local_attn<<<1024, 128, 0, stream>>>(attn, rowAgg, gn_w, gn_b, out);
}

// Round 5
// 113.759 us; speedup vs baseline: 1.7810x; 1.7810x over previous
//
#include <hip/hip_runtime.h>
#include <hip/hip_bf16.h>

#define B_    8
#define CIN   256
#define COUT  768
#define G_    24
#define PW    40         // padded row width (16B-aligned rows)
#define PLANE 1440       // 40*36
#define EPS_  1e-5f

typedef float f32x4 __attribute__((ext_vector_type(4)));
typedef short s16x8 __attribute__((ext_vector_type(8)));
typedef unsigned short ushort_t;
typedef unsigned short u16x4 __attribute__((ext_vector_type(4)));
typedef unsigned long long ull_t;

// LDS-only fence: compiler reordering barrier + s_waitcnt lgkmcnt(0).
// Does NOT wait vmcnt -> global prefetch loads stay in flight.
#define LDS_FENCE() do { asm volatile("" ::: "memory"); \
                         __builtin_amdgcn_s_waitcnt(0xC07F); \
                         asm volatile("" ::: "memory"); } while (0)

static __device__ __forceinline__ ushort_t f2bf(float f) {
    union { float f; unsigned u; } a; a.f = f;
    const unsigned u = a.u;
    const unsigned r = u + 0x7FFFu + ((u >> 16) & 1u);
    return (ushort_t)(r >> 16);
}
static __device__ __forceinline__ float bf2f(ushort_t h) {
    union { unsigned u; float f; } a; a.u = ((unsigned)h) << 16; return a.f;
}
static __device__ __forceinline__ void st4(float* dst, u16x4 v) {
    *(f32x4*)dst = f32x4{ bf2f(v[0]), bf2f(v[1]), bf2f(v[2]), bf2f(v[3]) };
}
static __device__ __forceinline__ unsigned pk2(float lo, float hi) {
    return (unsigned)f2bf(lo) | ((unsigned)f2bf(hi) << 16);
}

// ---------------- Kernel 0: one-time prep --------------------------------
// blocks 0..511 : transpose+convert x[b][k][n] fp32 -> xT[b][n][k] bf16
//                 (64x64 tiles via LDS; read and write both coalesced)
// blocks 512+   : convert conv_w fp32 -> bf16 (layout unchanged [m][k])
__launch_bounds__(256)
__global__ void prep(const float* __restrict__ x, const float* __restrict__ wsrc,
                     ushort_t* __restrict__ xT, ushort_t* __restrict__ wbf) {
    const int bid = blockIdx.x;
    const int t = threadIdx.x;
    if (bid < 512) {
        const int nt = bid & 15, kt = (bid >> 4) & 3, b = bid >> 6;
        const int n0 = nt * 64, k0 = kt * 64;
        __shared__ float Ts[64][65];     // +1 pad: column reads 2-way free
        const int kr = t >> 2, c4 = t & 3;
        const float* src = x + (size_t)b * (CIN * 1024) + (size_t)(k0 + kr) * 1024 + n0 + c4 * 16;
        const float4 v0 = *(const float4*)(src + 0);
        const float4 v1 = *(const float4*)(src + 4);
        const float4 v2 = *(const float4*)(src + 8);
        const float4 v3 = *(const float4*)(src + 12);
        float* d = &Ts[kr][c4 * 16];
        *(float4*)(d + 0) = v0; *(float4*)(d + 4) = v1;
        *(float4*)(d + 8) = v2; *(float4*)(d + 12) = v3;
        __syncthreads();
        const int nr = t >> 2, k4 = t & 3;
        unsigned pk[8];
        #pragma unroll
        for (int i = 0; i < 8; ++i)
            pk[i] = pk2(Ts[k4 * 16 + 2 * i][nr], Ts[k4 * 16 + 2 * i + 1][nr]);
        ushort_t* dst = xT + (size_t)b * (1024 * 256) + (size_t)(n0 + nr) * 256 + k0 + k4 * 16;
        *(uint4*)(dst + 0) = uint4{ pk[0], pk[1], pk[2], pk[3] };
        *(uint4*)(dst + 8) = uint4{ pk[4], pk[5], pk[6], pk[7] };
    } else {
        const int wid = bid - 512;       // 96 blocks x 2048 elems
        const size_t idx = (size_t)wid * 2048 + (size_t)t * 8;
        const float4 u0 = *(const float4*)(wsrc + idx);
        const float4 u1 = *(const float4*)(wsrc + idx + 4);
        uint4 o;
        o.x = pk2(u0.x, u0.y); o.y = pk2(u0.z, u0.w);
        o.z = pk2(u1.x, u1.y); o.w = pk2(u1.z, u1.w);
        *(uint4*)(wbf + idx) = o;
    }
}

// ---------------- Kernel 1: bf16 MFMA GEMM -> attn + rowAgg ------------------
// 128 m-rows per block (grid y = 6): each wave computes TWO 16-row strips that
// SHARE the B fragments -> per K-step 2 A-loads + 4 ds_read_b128 + 8 MFMA
// (B-read cost per MFMA halved vs the 64-row version), and the redundant
// B-panel re-staging across y-blocks halves (12 -> 6 passes over xT).
__launch_bounds__(256)
__global__ void conv_gemm(const ushort_t* __restrict__ wbf, const ushort_t* __restrict__ xT,
                          const float* __restrict__ bias, ushort_t* __restrict__ attn,
                          float* __restrict__ rowAgg) {
    const int t = threadIdx.x;
    const int wv = t >> 6, lane = t & 63;
    const int q = lane >> 4, l15 = lane & 15;
    const int m0 = blockIdx.y * 128;
    const int mw = wv * 32;              // wave's first m row (2 strips of 16)
    const int n_t = blockIdx.x * 64;
    const int b = n_t >> 10, nl0 = n_t & 1023;
    const int y0 = nl0 >> 5;

    __shared__ ushort_t Bs[64][264];     // [n][k] bf16, row stride 264 hw (33792 B)
    ushort_t (*Ct)[2][44] = (ushort_t (*)[2][44])(&Bs[0][0]);               // [128][2][44] = 22528 B
    float (*red)[11]      = (float (*)[11])((char*)(&Bs[0][0]) + 128 * 2 * 44 * 2);  // [256][11] = 11264 B

    // ---- stage B: xT[b][nl0+row][0..255] bf16 -> Bs[row][k] (straight copy)
    {
        const ushort_t* src = xT + (size_t)b * (1024 * 256) + (size_t)nl0 * 256;
        #pragma unroll
        for (int i = 0; i < 8; ++i) {
            const int id = i * 256 + t;
            const int row = id >> 5, seg = id & 31;
            *(s16x8*)&Bs[row][seg * 8] = *(const s16x8*)(src + row * 256 + seg * 8);
        }
    }
    __syncthreads();

    const ushort_t* aPf0 = wbf + (size_t)(m0 + mw + l15) * 256 + q * 8;
    const ushort_t* aPf1 = aPf0 + 16 * 256;

    f32x4 acc0[4] = {{0,0,0,0},{0,0,0,0},{0,0,0,0},{0,0,0,0}};
    f32x4 acc1[4] = {{0,0,0,0},{0,0,0,0},{0,0,0,0},{0,0,0,0}};
    #pragma unroll
    for (int k0 = 0; k0 < 256; k0 += 32) {
        const s16x8 a0 = *(const s16x8*)(aPf0 + k0);
        const s16x8 a1 = *(const s16x8*)(aPf1 + k0);
        const int kk = k0 + q * 8;
        const s16x8 b0 = *(const s16x8*)&Bs[l15 +  0][kk];
        const s16x8 b1 = *(const s16x8*)&Bs[l15 + 16][kk];
        const s16x8 b2 = *(const s16x8*)&Bs[l15 + 32][kk];
        const s16x8 b3 = *(const s16x8*)&Bs[l15 + 48][kk];
        acc0[0] = __builtin_amdgcn_mfma_f32_16x16x32_bf16(a0, b0, acc0[0], 0, 0, 0);
        acc0[1] = __builtin_amdgcn_mfma_f32_16x16x32_bf16(a0, b1, acc0[1], 0, 0, 0);
        acc0[2] = __builtin_amdgcn_mfma_f32_16x16x32_bf16(a0, b2, acc0[2], 0, 0, 0);
        acc0[3] = __builtin_amdgcn_mfma_f32_16x16x32_bf16(a0, b3, acc0[3], 0, 0, 0);
        acc1[0] = __builtin_amdgcn_mfma_f32_16x16x32_bf16(a1, b0, acc1[0], 0, 0, 0);
        acc1[1] = __builtin_amdgcn_mfma_f32_16x16x32_bf16(a1, b1, acc1[1], 0, 0, 0);
        acc1[2] = __builtin_amdgcn_mfma_f32_16x16x32_bf16(a1, b2, acc1[2], 0, 0, 0);
        acc1[3] = __builtin_amdgcn_mfma_f32_16x16x32_bf16(a1, b3, acc1[3], 0, 0, 0);
    }
    __syncthreads();   // Bs dead; Ct/red aliasing begins

    float bb0[4], bb1[4];
    #pragma unroll
    for (int r = 0; r < 4; ++r) {
        bb0[r] = bias[m0 + mw + q * 4 + r];
        bb1[r] = bias[m0 + mw + 16 + q * 4 + r];
    }
    #pragma unroll
    for (int j = 0; j < 4; ++j) {
        const int yy = j >> 1, xx = (j & 1) * 16 + l15;
        #pragma unroll
        for (int r = 0; r < 4; ++r) {
            Ct[mw + q * 4 + r][yy][2 + xx]      = f2bf(acc0[j][r] + bb0[r]);
            Ct[mw + 16 + q * 4 + r][yy][2 + xx] = f2bf(acc1[j][r] + bb1[r]);
        }
    }
    #pragma unroll
    for (int it = 0; it < 4; ++it) {
        const int id = it * 256 + t;
        const int m = id >> 3, yy = (id >> 2) & 1, pos = id & 3;
        const int us = (pos == 0) ? 0 : (32 + 2 * pos);
        *(unsigned*)&Ct[m][yy][us] = 0u;
    }
    __syncthreads();

    ushort_t* pb = attn + ((size_t)(b * COUT + m0)) * PLANE;
    #pragma unroll
    for (int it = 0; it < 10; ++it) {
        const int id = it * 256 + t;
        const int m = id / 20, rem = id % 20, yy = rem / 10, s = rem % 10;
        const ull_t v = *(const ull_t*)&Ct[m][yy][s * 4];
        *(ull_t*)(pb + (size_t)m * PLANE + (y0 + yy + 2) * PW + s * 4) = v;
    }
    if (y0 == 0 || y0 == 30) {
        const int rowA = (y0 == 0) ? 0 : 34;
        #pragma unroll
        for (int it = 0; it < 10; ++it) {
            const int id = it * 256 + t;
            const int m = id / 20, rem = id % 20, yy = rem / 10, s = rem % 10;
            *(ull_t*)(pb + (size_t)m * PLANE + (rowA + yy) * PW + s * 4) = 0ull;
        }
    }

    {
        const int gi = t >> 6, yy = (t >> 5) & 1, c = t & 31;
        const int m = gi * 32 + c;
        float lin = 0.f, sq = 0.f, e0 = 0.f, e1 = 0.f, e30 = 0.f, e31 = 0.f;
        #pragma unroll
        for (int u = 0; u < 9; ++u) {
            const ull_t vv = *(const ull_t*)&Ct[m][yy][u * 4];
            const unsigned lo = (unsigned)vv, hi = (unsigned)(vv >> 32);
            union { unsigned u; float f; } f0, f1, f2, f3;
            f0.u = lo << 16; f1.u = lo & 0xffff0000u;
            f2.u = hi << 16; f3.u = hi & 0xffff0000u;
            lin += (f0.f + f1.f) + (f2.f + f3.f);
            sq  += (f0.f * f0.f + f1.f * f1.f) + (f2.f * f2.f + f3.f * f3.f);
            if (u == 0) { e0 = f2.f; e1 = f3.f; }
            if (u == 8) { e30 = f0.f; e31 = f1.f; }
        }
        red[t][0] = lin; red[t][1] = sq;
        red[t][2] = e0;  red[t][3] = e0 * e0;
        red[t][4] = e1;  red[t][5] = e1 * e1;
        red[t][6] = e30; red[t][7] = e30 * e30;
        red[t][8] = e31; red[t][9] = e31 * e31;
    }
    __syncthreads();
    if (t < 80) {
        const int s = t % 10, gy = t / 10;
        const int gi = gy >> 1, yy = gy & 1;
        float sum = 0.f;
        #pragma unroll
        for (int c = 0; c < 32; ++c) sum += red[gi * 64 + yy * 32 + c][s];
        const int g = blockIdx.y * 4 + gi;
        rowAgg[(((size_t)b * G_ + g) * 32 + (y0 + yy)) * 10 + s] = sum;
    }
}

// ---------------- Kernel 2: local attention — 2-wave blocks, 2-row slabs.
// EXACT R2 structure (proven ~19.5 µs): wave = channel half; wave-private
// double-buffered LDS staging, rolled loops (full unroll spilled @256 VGPR in
// R4), fence-only pipeline, ONE __syncthreads for the cross-wave sal exchange.
// Only addition: bijective XCD blockIdx swizzle (one batch image per XCD L2).
__launch_bounds__(128)
__global__ void local_attn(const ushort_t* __restrict__ attn,
                           const float* __restrict__ rowAgg,
                           const float* __restrict__ gn_w, const float* __restrict__ gn_b,
                           float* __restrict__ out) {
    const int bx = blockIdx.x;           // 1024 = 8 XCD chunks x 128
    const int wid = (bx & 7) * 128 + (bx >> 3);   // bijective XCD swizzle
    const int b = wid >> 7;
    const int n = (wid >> 4) & 7;
    const int i0 = (wid & 15) * 2;       // first image row of the 2-row slab
    const int t = threadIdx.x;           // 128
    const int h = t >> 6;                // wave index = channel half
    const int lane = t & 63;
    const int r = lane >> 5;             // row within slab
    const int j = lane & 31;             // pixel column

    __shared__ float KB[2][2][240];      // [half][buf][6 rows x 40]
    __shared__ float QB[2][2][240];
    __shared__ float ex[128][27];        // sal exchange, stride-27 conflict-free
    __shared__ float rpL[96][5], rp2L[96][5];
    __shared__ float s_m[75], s_r[75];
    __shared__ float s_rq[25], s_mq[25], s_rk[25], s_ck[25], s_rv[25], s_cv[25];
    __shared__ float s_gw[96], s_gb[96];

    if (t < 96) { s_gw[t] = gn_w[n * 96 + t]; s_gb[t] = gn_b[n * 96 + t]; }

    // ---- fused gnfin, phase 1: per-(group,row) window column sums ----------
    const float* rab = rowAgg + (size_t)((b * G_ + n * 3) * 32) * 10;
    if (t < 96) {
        const float* a = rab + (size_t)t * 10;
        const float S = a[0], Sq = a[1];
        const float e0 = a[2], q0 = a[3], e1 = a[4], q1 = a[5];
        const float e30 = a[6], q30 = a[7], e31 = a[8], q31 = a[9];
        rpL[t][0] = S - e30 - e31; rpL[t][1] = S - e31; rpL[t][2] = S;
        rpL[t][3] = S - e0;        rpL[t][4] = S - e0 - e1;
        rp2L[t][0] = Sq - q30 - q31; rp2L[t][1] = Sq - q31; rp2L[t][2] = Sq;
        rp2L[t][3] = Sq - q0;        rp2L[t][4] = Sq - q0 - q1;
    }
    __syncthreads();

    // ---- fused gnfin, phase 2: 75 (group,window) mean/rstd entries ---------
    if (t < 75) {
        const int gi = t / 25, p = t % 25;
        const int kw = p % 5, kh = p / 5;
        const int rb = gi * 32;
        float cs = 0.f, cs2 = 0.f;
        #pragma unroll
        for (int yy = 0; yy < 32; ++yy) { cs += rpL[rb + yy][kw]; cs2 += rp2L[rb + yy][kw]; }
        if (kh == 0)      { cs -= rpL[rb + 30][kw] + rpL[rb + 31][kw]; cs2 -= rp2L[rb + 30][kw] + rp2L[rb + 31][kw]; }
        else if (kh == 1) { cs -= rpL[rb + 31][kw];                    cs2 -= rp2L[rb + 31][kw]; }
        else if (kh == 3) { cs -= rpL[rb + 0][kw];                     cs2 -= rp2L[rb + 0][kw]; }
        else if (kh == 4) { cs -= rpL[rb + 0][kw] + rpL[rb + 1][kw];   cs2 -= rp2L[rb + 0][kw] + rp2L[rb + 1][kw]; }
        const float inv_n = 1.f / 32768.f;
        const float mean = cs * inv_n;
        const float var  = cs2 * inv_n - mean * mean;
        s_m[t] = mean;
        s_r[t] = rsqrtf(var + EPS_);
    }
    __syncthreads();

    if (t < 25) {
        const float mK = s_m[t],      rK = s_r[t];
        const float mQ = s_m[25 + t], rQ = s_r[25 + t];
        const float mV = s_m[50 + t], rV = s_r[50 + t];
        s_rk[t] = rK; s_ck[t] = mK * rK;
        s_rq[t] = rQ; s_mq[t] = mQ * rQ;
        s_rv[t] = rV; s_cv[t] = mV * rV;
    }
    __syncthreads();

    float rq[25]; float cQ = 0.f;
    #pragma unroll
    for (int p = 0; p < 25; ++p) { rq[p] = s_rq[p]; cQ += s_mq[p]; }

    // wave-private staging: padded rows i0..i0+5 (240 bf16/plane); 60 stagers
    const ushort_t* regB = attn + (size_t)(b * COUT + n * 96) * PLANE + i0 * PW;
    const bool stg = (lane < 60);
    const int eo = lane * 4;
    const int base = r * PW + j;

    const ushort_t* baseK = regB + (size_t)(h * 16) * PLANE;
    const ushort_t* baseQ = regB + (size_t)(32 + h * 16) * PLANE;
    const ushort_t* baseV = regB + (size_t)(64 + h * 16) * PLANE;

    u16x4 nK{0,0,0,0}, nQ{0,0,0,0}, fK{0,0,0,0}, fQ{0,0,0,0};
    if (stg) {
        const u16x4 c0K = *(const u16x4*)(baseK + eo);
        const u16x4 c0Q = *(const u16x4*)(baseQ + eo);
        st4(&KB[h][0][eo], c0K);
        st4(&QB[h][0][eo], c0Q);
        nK = *(const u16x4*)(baseK + (size_t)PLANE + eo);
        nQ = *(const u16x4*)(baseQ + (size_t)PLANE + eo);
        fK = *(const u16x4*)(baseK + 2 * (size_t)PLANE + eo);
        fQ = *(const u16x4*)(baseQ + 2 * (size_t)PLANE + eo);
    }
    LDS_FENCE();

    float sal[25];
    #pragma unroll
    for (int p = 0; p < 25; ++p) sal[p] = 0.f;
    float sumQ2 = 0.f, sumQB = 0.f;

    for (int cc = 0; cc < 16; ++cc) {
        const int buf = cc & 1;
        if (stg && cc < 15) {
            st4(&KB[h][buf ^ 1][eo], nK);
            st4(&QB[h][buf ^ 1][eo], nQ);
            nK = fK; nQ = fQ;
            if (cc < 13) {
                fK = *(const u16x4*)(baseK + (size_t)(cc + 3) * PLANE + eo);
                fQ = *(const u16x4*)(baseQ + (size_t)(cc + 3) * PLANE + eo);
            } else if (cc == 13) {   // tail: prefetch V planes 0 and 1
                fK = *(const u16x4*)(baseV + eo);
                fQ = *(const u16x4*)(baseV + (size_t)PLANE + eo);
            }
        }
        const int ch = h * 16 + cc;
        const float* qb = &QB[h][buf][base];
        const float* kb = &KB[h][buf][base];
        float qa0 = 0.f, qa1 = 0.f, qa2 = 0.f, qa3 = 0.f, qa4 = 0.f;
        #pragma unroll
        for (int kw = 0; kw < 5; ++kw) {
            qa0 += rq[0 * 5 + kw] * qb[0 * PW + kw];
            qa1 += rq[1 * 5 + kw] * qb[1 * PW + kw];
            qa2 += rq[2 * 5 + kw] * qb[2 * PW + kw];
            qa3 += rq[3 * 5 + kw] * qb[3 * PW + kw];
            qa4 += rq[4 * 5 + kw] * qb[4 * PW + kw];
        }
        const float qa = (qa0 + qa1) + (qa2 + qa3) + qa4;
        const float qk  = s_gw[32 + ch] * ((qa - cQ) * 0.04f) + s_gb[32 + ch];
        const float qk2 = qk * s_gw[ch];
        sumQ2 += qk2; sumQB += qk * s_gb[ch];
        #pragma unroll
        for (int kh = 0; kh < 5; ++kh)
            #pragma unroll
            for (int kw = 0; kw < 5; ++kw)
                sal[kh * 5 + kw] += qk2 * kb[kh * PW + kw];
        LDS_FENCE();
    }
    // after loop: nK = V plane 0, nQ = V plane 1 (rotated in via tail fetch)

    // cross-wave exchange (lane t <-> t^64): write partials + stage V0, barrier
    #pragma unroll
    for (int p = 0; p < 25; ++p) ex[t][p] = sal[p];
    ex[t][25] = sumQ2; ex[t][26] = sumQB;
    if (stg) st4(&KB[h][0][eo], nK);     // V0 -> buf0 (wave-private)
    __syncthreads();
    const int par = t ^ 64;
    #pragma unroll
    for (int p = 0; p < 25; ++p) sal[p] += ex[par][p];
    sumQ2 += ex[par][25]; sumQB += ex[par][26];

    u16x4 vA = nQ, vB{0,0,0,0};
    if (stg) vB = *(const u16x4*)(baseV + 2 * (size_t)PLANE + eo);  // V2 (post-barrier)

    #pragma unroll
    for (int p = 0; p < 25; ++p) sal[p] = s_rk[p] * sal[p] - s_ck[p] * sumQ2 + sumQB;

    const float scale = 0.17677669529663687f;  // 1/sqrt(32)
    float mmax = -3.4e38f;
    #pragma unroll
    for (int p = 0; p < 25; ++p) { sal[p] *= scale; mmax = fmaxf(mmax, sal[p]); }
    float ssum = 0.f;
    #pragma unroll
    for (int p = 0; p < 25; ++p) { sal[p] = __expf(sal[p] - mmax); ssum += sal[p]; }
    const float rs = 1.f / ssum;
    float cV2 = 0.f;
    #pragma unroll
    for (int p = 0; p < 25; ++p) {
        const float m = sal[p] * rs;
        sal[p] = m * s_rv[p];        // reuse sal as V-tap weights
        cV2 += m * s_cv[p];
    }
    LDS_FENCE();

    for (int cc = 0; cc < 16; ++cc) {
        const int buf = cc & 1;
        if (stg && cc < 15) {
            st4(&KB[h][buf ^ 1][eo], vA);
            vA = vB;
            if (cc < 13) vB = *(const u16x4*)(baseV + (size_t)(cc + 3) * PLANE + eo);
        }
        const int v = h * 16 + cc;
        const float* vb = &KB[h][buf][base];
        float a0 = 0.f, a1 = 0.f, a2 = 0.f, a3 = 0.f, a4 = 0.f;
        #pragma unroll
        for (int kw = 0; kw < 5; ++kw) {
            a0 += sal[0 * 5 + kw] * vb[0 * PW + kw];
            a1 += sal[1 * 5 + kw] * vb[1 * PW + kw];
            a2 += sal[2 * 5 + kw] * vb[2 * PW + kw];
            a3 += sal[3 * 5 + kw] * vb[3 * PW + kw];
            a4 += sal[4 * 5 + kw] * vb[4 * PW + kw];
        }
        const float acc = (a0 + a1) + (a2 + a3) + a4;
        out[((size_t)(b * 256 + n * 32 + v) * 32 + (i0 + r)) * 32 + j] =
            s_gw[64 + v] * acc + (s_gb[64 + v] - s_gw[64 + v] * cV2);
        LDS_FENCE();
    }
}

extern "C" void kernel_launch(void* const* d_in, const int* in_sizes, int n_in,
                              void* d_out, int out_size, void* d_ws, size_t ws_size,
                              hipStream_t stream) {
    const float* x      = (const float*)d_in[0];
    const float* conv_w = (const float*)d_in[1];
    const float* conv_b = (const float*)d_in[2];
    const float* gn_w   = (const float*)d_in[3];
    const float* gn_b   = (const float*)d_in[4];
    float* out = (float*)d_out;

    // ws: attn bf16 padded | rowAgg f32 | xT bf16 | wbf bf16
    ushort_t* attn    = (ushort_t*)d_ws;                    // 8,847,360 ushorts
    float*    rowAgg  = (float*)(attn + 8847360);           // 61,440 floats
    ushort_t* xT      = (ushort_t*)(rowAgg + 61440);        // 2,097,152 ushorts
    ushort_t* wbf     = xT + 2097152;                       // 196,608 ushorts

    prep<<<608, 256, 0, stream>>>(x, conv_w, xT, wbf);
    conv_gemm<<<dim3(128, 6), 256, 0, stream>>>(wbf, xT, conv_b, attn, rowAgg);
    local_attn<<<1024, 128, 0, stream>>>(attn, rowAgg, gn_w, gn_b, out);
}

// Round 6
// 109.277 us; speedup vs baseline: 1.8540x; 1.0410x over previous
//
#include <hip/hip_runtime.h>
#include <hip/hip_bf16.h>

#define B_    8
#define CIN   256
#define COUT  768
#define G_    24
#define PW    40         // padded row width (16B-aligned rows)
#define PLANE 1440       // 40*36
#define EPS_  1e-5f

typedef float f32x4 __attribute__((ext_vector_type(4)));
typedef short s16x8 __attribute__((ext_vector_type(8)));
typedef unsigned short ushort_t;
typedef unsigned short u16x4 __attribute__((ext_vector_type(4)));
typedef unsigned long long ull_t;

typedef const __attribute__((address_space(1))) void* gas_ptr_t;
typedef __attribute__((address_space(3))) void* las_ptr_t;

// LDS-only fence: compiler reordering barrier + s_waitcnt lgkmcnt(0).
// Does NOT wait vmcnt -> global prefetch loads stay in flight.
#define LDS_FENCE() do { asm volatile("" ::: "memory"); \
                         __builtin_amdgcn_s_waitcnt(0xC07F); \
                         asm volatile("" ::: "memory"); } while (0)

static __device__ __forceinline__ ushort_t f2bf(float f) {
    union { float f; unsigned u; } a; a.f = f;
    const unsigned u = a.u;
    const unsigned r = u + 0x7FFFu + ((u >> 16) & 1u);
    return (ushort_t)(r >> 16);
}
static __device__ __forceinline__ float bf2f(ushort_t h) {
    union { unsigned u; float f; } a; a.u = ((unsigned)h) << 16; return a.f;
}
static __device__ __forceinline__ void st4(float* dst, u16x4 v) {
    *(f32x4*)dst = f32x4{ bf2f(v[0]), bf2f(v[1]), bf2f(v[2]), bf2f(v[3]) };
}
static __device__ __forceinline__ unsigned pk2(float lo, float hi) {
    return (unsigned)f2bf(lo) | ((unsigned)f2bf(hi) << 16);
}

// ---------------- Kernel 0: one-time prep --------------------------------
// blocks 0..511 : transpose+convert x[b][k][n] fp32 -> xT[b][n][k] bf16
// blocks 512+   : convert conv_w fp32 -> bf16 (layout unchanged [m][k])
__launch_bounds__(256)
__global__ void prep(const float* __restrict__ x, const float* __restrict__ wsrc,
                     ushort_t* __restrict__ xT, ushort_t* __restrict__ wbf) {
    const int bid = blockIdx.x;
    const int t = threadIdx.x;
    if (bid < 512) {
        const int nt = bid & 15, kt = (bid >> 4) & 3, b = bid >> 6;
        const int n0 = nt * 64, k0 = kt * 64;
        __shared__ float Ts[64][65];     // +1 pad: column reads 2-way free
        const int kr = t >> 2, c4 = t & 3;
        const float* src = x + (size_t)b * (CIN * 1024) + (size_t)(k0 + kr) * 1024 + n0 + c4 * 16;
        const float4 v0 = *(const float4*)(src + 0);
        const float4 v1 = *(const float4*)(src + 4);
        const float4 v2 = *(const float4*)(src + 8);
        const float4 v3 = *(const float4*)(src + 12);
        float* d = &Ts[kr][c4 * 16];
        *(float4*)(d + 0) = v0; *(float4*)(d + 4) = v1;
        *(float4*)(d + 8) = v2; *(float4*)(d + 12) = v3;
        __syncthreads();
        const int nr = t >> 2, k4 = t & 3;
        unsigned pk[8];
        #pragma unroll
        for (int i = 0; i < 8; ++i)
            pk[i] = pk2(Ts[k4 * 16 + 2 * i][nr], Ts[k4 * 16 + 2 * i + 1][nr]);
        ushort_t* dst = xT + (size_t)b * (1024 * 256) + (size_t)(n0 + nr) * 256 + k0 + k4 * 16;
        *(uint4*)(dst + 0) = uint4{ pk[0], pk[1], pk[2], pk[3] };
        *(uint4*)(dst + 8) = uint4{ pk[4], pk[5], pk[6], pk[7] };
    } else {
        const int wid = bid - 512;       // 96 blocks x 2048 elems
        const size_t idx = (size_t)wid * 2048 + (size_t)t * 8;
        const float4 u0 = *(const float4*)(wsrc + idx);
        const float4 u1 = *(const float4*)(wsrc + idx + 4);
        uint4 o;
        o.x = pk2(u0.x, u0.y); o.y = pk2(u0.z, u0.w);
        o.z = pk2(u1.x, u1.y); o.w = pk2(u1.z, u1.w);
        *(uint4*)(wbf + idx) = o;
    }
}

// ---------------- Kernel 1: bf16 MFMA GEMM -> attn + rowAgg ------------------
// B-stage via global_load_lds (width 16, no VGPR round trip). LDS layout is
// FLAT [64 rows][256 k] (32768 B -> 5 blocks/CU, was 4) with an XOR data
// swizzle applied on the GLOBAL source address (16B chunk s holds chunk
// s^(row&7)); K-loop reads apply the same XOR -> conflict level unchanged.
__launch_bounds__(256)
__global__ void conv_gemm(const ushort_t* __restrict__ wbf, const ushort_t* __restrict__ xT,
                          const float* __restrict__ bias, ushort_t* __restrict__ attn,
                          float* __restrict__ rowAgg) {
    const int t = threadIdx.x;
    const int wv = t >> 6, lane = t & 63;
    const int q = lane >> 4, l15 = lane & 15;
    const int m0 = blockIdx.y * 64;
    const int mw = wv * 16;
    const int n_t = blockIdx.x * 64;
    const int b = n_t >> 10, nl0 = n_t & 1023;
    const int y0 = nl0 >> 5;

    __shared__ ushort_t Bs[16384];       // flat [row][k] bf16, 32768 B
    ushort_t (*Ct)[2][44] = (ushort_t (*)[2][44])(&Bs[0]);
    float (*red)[11]      = (float (*)[11])((char*)(&Bs[0]) + 64 * 2 * 44 * 2);

    // ---- stage B: global_load_lds, source-swizzled, LDS lane-linear --------
    {
        const ushort_t* src = xT + (size_t)b * (1024 * 256) + (size_t)nl0 * 256;
        #pragma unroll
        for (int i = 0; i < 8; ++i) {
            const int idx = i * 256 + t;          // 16B chunk index 0..2047
            const int row = idx >> 5, s = idx & 31;
            const ushort_t* gp = src + row * 256 + ((s ^ (row & 7)) << 3);
            __builtin_amdgcn_global_load_lds((gas_ptr_t)gp, (las_ptr_t)&Bs[idx * 8],
                                             16, 0, 0);
        }
    }
    __syncthreads();   // drains vmcnt -> Bs ready

    const ushort_t* aPf = wbf + (size_t)(m0 + mw + l15) * 256 + q * 8;
    const int e7 = l15 & 7;

    f32x4 acc[4] = {{0,0,0,0},{0,0,0,0},{0,0,0,0},{0,0,0,0}};
    #pragma unroll
    for (int k0 = 0; k0 < 256; k0 += 32) {
        const s16x8 a = *(const s16x8*)(aPf + k0);
        const int sx = ((k0 >> 3) + q) ^ e7;      // swizzled 16B chunk index
        const ushort_t* bp = &Bs[l15 * 256 + sx * 8];
        const s16x8 b0 = *(const s16x8*)(bp +  0 * 256);
        const s16x8 b1 = *(const s16x8*)(bp + 16 * 256);
        const s16x8 b2 = *(const s16x8*)(bp + 32 * 256);
        const s16x8 b3 = *(const s16x8*)(bp + 48 * 256);
        acc[0] = __builtin_amdgcn_mfma_f32_16x16x32_bf16(a, b0, acc[0], 0, 0, 0);
        acc[1] = __builtin_amdgcn_mfma_f32_16x16x32_bf16(a, b1, acc[1], 0, 0, 0);
        acc[2] = __builtin_amdgcn_mfma_f32_16x16x32_bf16(a, b2, acc[2], 0, 0, 0);
        acc[3] = __builtin_amdgcn_mfma_f32_16x16x32_bf16(a, b3, acc[3], 0, 0, 0);
    }
    __syncthreads();   // Bs dead; Ct/red aliasing begins

    float bb[4];
    #pragma unroll
    for (int r = 0; r < 4; ++r) bb[r] = bias[m0 + mw + q * 4 + r];
    #pragma unroll
    for (int j = 0; j < 4; ++j) {
        const int yy = j >> 1, xx = (j & 1) * 16 + l15;
        #pragma unroll
        for (int r = 0; r < 4; ++r)
            Ct[mw + q * 4 + r][yy][2 + xx] = f2bf(acc[j][r] + bb[r]);
    }
    #pragma unroll
    for (int it = 0; it < 2; ++it) {
        const int id = it * 256 + t;
        const int m = id >> 3, yy = (id >> 2) & 1, pos = id & 3;
        const int us = (pos == 0) ? 0 : (32 + 2 * pos);
        *(unsigned*)&Ct[m][yy][us] = 0u;
    }
    __syncthreads();

    ushort_t* pb = attn + ((size_t)(b * COUT + m0)) * PLANE;
    #pragma unroll
    for (int it = 0; it < 5; ++it) {
        const int id = it * 256 + t;
        const int m = id / 20, rem = id % 20, yy = rem / 10, s = rem % 10;
        const ull_t v = *(const ull_t*)&Ct[m][yy][s * 4];
        *(ull_t*)(pb + (size_t)m * PLANE + (y0 + yy + 2) * PW + s * 4) = v;
    }
    if (y0 == 0 || y0 == 30) {
        const int rowA = (y0 == 0) ? 0 : 34;
        #pragma unroll
        for (int it = 0; it < 5; ++it) {
            const int id = it * 256 + t;
            const int m = id / 20, rem = id % 20, yy = rem / 10, s = rem % 10;
            *(ull_t*)(pb + (size_t)m * PLANE + (rowA + yy) * PW + s * 4) = 0ull;
        }
    }

    if (t < 128) {
        const int gi = t >> 6, yy = (t >> 5) & 1, c = t & 31;
        const int m = gi * 32 + c;
        float lin = 0.f, sq = 0.f, e0 = 0.f, e1 = 0.f, e30 = 0.f, e31 = 0.f;
        #pragma unroll
        for (int u = 0; u < 9; ++u) {
            const ull_t vv = *(const ull_t*)&Ct[m][yy][u * 4];
            const unsigned lo = (unsigned)vv, hi = (unsigned)(vv >> 32);
            union { unsigned u; float f; } f0, f1, f2, f3;
            f0.u = lo << 16; f1.u = lo & 0xffff0000u;
            f2.u = hi << 16; f3.u = hi & 0xffff0000u;
            lin += (f0.f + f1.f) + (f2.f + f3.f);
            sq  += (f0.f * f0.f + f1.f * f1.f) + (f2.f * f2.f + f3.f * f3.f);
            if (u == 0) { e0 = f2.f; e1 = f3.f; }
            if (u == 8) { e30 = f0.f; e31 = f1.f; }
        }
        red[t][0] = lin; red[t][1] = sq;
        red[t][2] = e0;  red[t][3] = e0 * e0;
        red[t][4] = e1;  red[t][5] = e1 * e1;
        red[t][6] = e30; red[t][7] = e30 * e30;
        red[t][8] = e31; red[t][9] = e31 * e31;
    }
    __syncthreads();
    if (t < 40) {
        const int s = t % 10, gy = t / 10;
        const int gi = gy >> 1, yy = gy & 1;
        float sum = 0.f;
        #pragma unroll
        for (int c = 0; c < 32; ++c) sum += red[gi * 64 + yy * 32 + c][s];
        const int g = blockIdx.y * 2 + gi;
        rowAgg[(((size_t)b * G_ + g) * 32 + (y0 + yy)) * 10 + s] = sum;
    }
}

// ---------------- Kernel 2: local attention — 2-wave blocks, 2-row slabs.
// Proven R2/R3 structure (no XCD swizzle: L3-resident working set, swizzle is
// neutral-to-negative). Wave = channel half; wave-private double-buffered LDS
// staging, fence-only pipeline, ONE __syncthreads for the sal exchange. ------
__launch_bounds__(128)
__global__ void local_attn(const ushort_t* __restrict__ attn,
                           const float* __restrict__ rowAgg,
                           const float* __restrict__ gn_w, const float* __restrict__ gn_b,
                           float* __restrict__ out) {
    const int wid = blockIdx.x;          // 1024 = b(8) x n(8) x slab(16)
    const int b = wid >> 7;
    const int n = (wid >> 4) & 7;
    const int i0 = (wid & 15) * 2;       // first image row of the 2-row slab
    const int t = threadIdx.x;           // 128
    const int h = t >> 6;                // wave index = channel half
    const int lane = t & 63;
    const int r = lane >> 5;             // row within slab
    const int j = lane & 31;             // pixel column

    __shared__ float KB[2][2][240];      // [half][buf][6 rows x 40]
    __shared__ float QB[2][2][240];
    __shared__ float ex[128][27];        // sal exchange, stride-27 conflict-free
    __shared__ float rpL[96][5], rp2L[96][5];
    __shared__ float s_m[75], s_r[75];
    __shared__ float s_rq[25], s_mq[25], s_rk[25], s_ck[25], s_rv[25], s_cv[25];
    __shared__ float s_gw[96], s_gb[96];

    if (t < 96) { s_gw[t] = gn_w[n * 96 + t]; s_gb[t] = gn_b[n * 96 + t]; }

    // ---- fused gnfin, phase 1: per-(group,row) window column sums ----------
    const float* rab = rowAgg + (size_t)((b * G_ + n * 3) * 32) * 10;
    if (t < 96) {
        const float* a = rab + (size_t)t * 10;
        const float S = a[0], Sq = a[1];
        const float e0 = a[2], q0 = a[3], e1 = a[4], q1 = a[5];
        const float e30 = a[6], q30 = a[7], e31 = a[8], q31 = a[9];
        rpL[t][0] = S - e30 - e31; rpL[t][1] = S - e31; rpL[t][2] = S;
        rpL[t][3] = S - e0;        rpL[t][4] = S - e0 - e1;
        rp2L[t][0] = Sq - q30 - q31; rp2L[t][1] = Sq - q31; rp2L[t][2] = Sq;
        rp2L[t][3] = Sq - q0;        rp2L[t][4] = Sq - q0 - q1;
    }
    __syncthreads();

    // ---- fused gnfin, phase 2: 75 (group,window) mean/rstd entries ---------
    if (t < 75) {
        const int gi = t / 25, p = t % 25;
        const int kw = p % 5, kh = p / 5;
        const int rb = gi * 32;
        float cs = 0.f, cs2 = 0.f;
        #pragma unroll
        for (int yy = 0; yy < 32; ++yy) { cs += rpL[rb + yy][kw]; cs2 += rp2L[rb + yy][kw]; }
        if (kh == 0)      { cs -= rpL[rb + 30][kw] + rpL[rb + 31][kw]; cs2 -= rp2L[rb + 30][kw] + rp2L[rb + 31][kw]; }
        else if (kh == 1) { cs -= rpL[rb + 31][kw];                    cs2 -= rp2L[rb + 31][kw]; }
        else if (kh == 3) { cs -= rpL[rb + 0][kw];                     cs2 -= rp2L[rb + 0][kw]; }
        else if (kh == 4) { cs -= rpL[rb + 0][kw] + rpL[rb + 1][kw];   cs2 -= rp2L[rb + 0][kw] + rp2L[rb + 1][kw]; }
        const float inv_n = 1.f / 32768.f;
        const float mean = cs * inv_n;
        const float var  = cs2 * inv_n - mean * mean;
        s_m[t] = mean;
        s_r[t] = rsqrtf(var + EPS_);
    }
    __syncthreads();

    if (t < 25) {
        const float mK = s_m[t],      rK = s_r[t];
        const float mQ = s_m[25 + t], rQ = s_r[25 + t];
        const float mV = s_m[50 + t], rV = s_r[50 + t];
        s_rk[t] = rK; s_ck[t] = mK * rK;
        s_rq[t] = rQ; s_mq[t] = mQ * rQ;
        s_rv[t] = rV; s_cv[t] = mV * rV;
    }
    __syncthreads();

    float rq[25]; float cQ = 0.f;
    #pragma unroll
    for (int p = 0; p < 25; ++p) { rq[p] = s_rq[p]; cQ += s_mq[p]; }

    // wave-private staging: padded rows i0..i0+5 (240 bf16/plane); 60 stagers
    const ushort_t* regB = attn + (size_t)(b * COUT + n * 96) * PLANE + i0 * PW;
    const bool stg = (lane < 60);
    const int eo = lane * 4;
    const int base = r * PW + j;

    const ushort_t* baseK = regB + (size_t)(h * 16) * PLANE;
    const ushort_t* baseQ = regB + (size_t)(32 + h * 16) * PLANE;
    const ushort_t* baseV = regB + (size_t)(64 + h * 16) * PLANE;

    u16x4 nK{0,0,0,0}, nQ{0,0,0,0}, fK{0,0,0,0}, fQ{0,0,0,0};
    if (stg) {
        const u16x4 c0K = *(const u16x4*)(baseK + eo);
        const u16x4 c0Q = *(const u16x4*)(baseQ + eo);
        st4(&KB[h][0][eo], c0K);
        st4(&QB[h][0][eo], c0Q);
        nK = *(const u16x4*)(baseK + (size_t)PLANE + eo);
        nQ = *(const u16x4*)(baseQ + (size_t)PLANE + eo);
        fK = *(const u16x4*)(baseK + 2 * (size_t)PLANE + eo);
        fQ = *(const u16x4*)(baseQ + 2 * (size_t)PLANE + eo);
    }
    LDS_FENCE();

    float sal[25];
    #pragma unroll
    for (int p = 0; p < 25; ++p) sal[p] = 0.f;
    float sumQ2 = 0.f, sumQB = 0.f;

    for (int cc = 0; cc < 16; ++cc) {
        const int buf = cc & 1;
        if (stg && cc < 15) {
            st4(&KB[h][buf ^ 1][eo], nK);
            st4(&QB[h][buf ^ 1][eo], nQ);
            nK = fK; nQ = fQ;
            if (cc < 13) {
                fK = *(const u16x4*)(baseK + (size_t)(cc + 3) * PLANE + eo);
                fQ = *(const u16x4*)(baseQ + (size_t)(cc + 3) * PLANE + eo);
            } else if (cc == 13) {   // tail: prefetch V planes 0 and 1
                fK = *(const u16x4*)(baseV + eo);
                fQ = *(const u16x4*)(baseV + (size_t)PLANE + eo);
            }
        }
        const int ch = h * 16 + cc;
        const float* qb = &QB[h][buf][base];
        const float* kb = &KB[h][buf][base];
        float qa0 = 0.f, qa1 = 0.f, qa2 = 0.f, qa3 = 0.f, qa4 = 0.f;
        #pragma unroll
        for (int kw = 0; kw < 5; ++kw) {
            qa0 += rq[0 * 5 + kw] * qb[0 * PW + kw];
            qa1 += rq[1 * 5 + kw] * qb[1 * PW + kw];
            qa2 += rq[2 * 5 + kw] * qb[2 * PW + kw];
            qa3 += rq[3 * 5 + kw] * qb[3 * PW + kw];
            qa4 += rq[4 * 5 + kw] * qb[4 * PW + kw];
        }
        const float qa = (qa0 + qa1) + (qa2 + qa3) + qa4;
        const float qk  = s_gw[32 + ch] * ((qa - cQ) * 0.04f) + s_gb[32 + ch];
        const float qk2 = qk * s_gw[ch];
        sumQ2 += qk2; sumQB += qk * s_gb[ch];
        #pragma unroll
        for (int kh = 0; kh < 5; ++kh)
            #pragma unroll
            for (int kw = 0; kw < 5; ++kw)
                sal[kh * 5 + kw] += qk2 * kb[kh * PW + kw];
        LDS_FENCE();
    }
    // after loop: nK = V plane 0, nQ = V plane 1 (rotated in via tail fetch)

    // cross-wave exchange (lane t <-> t^64): write partials + stage V0, barrier
    #pragma unroll
    for (int p = 0; p < 25; ++p) ex[t][p] = sal[p];
    ex[t][25] = sumQ2; ex[t][26] = sumQB;
    if (stg) st4(&KB[h][0][eo], nK);     // V0 -> buf0 (wave-private)
    __syncthreads();
    const int par = t ^ 64;
    #pragma unroll
    for (int p = 0; p < 25; ++p) sal[p] += ex[par][p];
    sumQ2 += ex[par][25]; sumQB += ex[par][26];

    u16x4 vA = nQ, vB{0,0,0,0};
    if (stg) vB = *(const u16x4*)(baseV + 2 * (size_t)PLANE + eo);  // V2 (post-barrier)

    #pragma unroll
    for (int p = 0; p < 25; ++p) sal[p] = s_rk[p] * sal[p] - s_ck[p] * sumQ2 + sumQB;

    const float scale = 0.17677669529663687f;  // 1/sqrt(32)
    float mmax = -3.4e38f;
    #pragma unroll
    for (int p = 0; p < 25; ++p) { sal[p] *= scale; mmax = fmaxf(mmax, sal[p]); }
    float ssum = 0.f;
    #pragma unroll
    for (int p = 0; p < 25; ++p) { sal[p] = __expf(sal[p] - mmax); ssum += sal[p]; }
    const float rs = 1.f / ssum;
    float cV2 = 0.f;
    #pragma unroll
    for (int p = 0; p < 25; ++p) {
        const float m = sal[p] * rs;
        sal[p] = m * s_rv[p];        // reuse sal as V-tap weights
        cV2 += m * s_cv[p];
    }
    LDS_FENCE();

    for (int cc = 0; cc < 16; ++cc) {
        const int buf = cc & 1;
        if (stg && cc < 15) {
            st4(&KB[h][buf ^ 1][eo], vA);
            vA = vB;
            if (cc < 13) vB = *(const u16x4*)(baseV + (size_t)(cc + 3) * PLANE + eo);
        }
        const int v = h * 16 + cc;
        const float* vb = &KB[h][buf][base];
        float a0 = 0.f, a1 = 0.f, a2 = 0.f, a3 = 0.f, a4 = 0.f;
        #pragma unroll
        for (int kw = 0; kw < 5; ++kw) {
            a0 += sal[0 * 5 + kw] * vb[0 * PW + kw];
            a1 += sal[1 * 5 + kw] * vb[1 * PW + kw];
            a2 += sal[2 * 5 + kw] * vb[2 * PW + kw];
            a3 += sal[3 * 5 + kw] * vb[3 * PW + kw];
            a4 += sal[4 * 5 + kw] * vb[4 * PW + kw];
        }
        const float acc = (a0 + a1) + (a2 + a3) + a4;
        out[((size_t)(b * 256 + n * 32 + v) * 32 + (i0 + r)) * 32 + j] =
            s_gw[64 + v] * acc + (s_gb[64 + v] - s_gw[64 + v] * cV2);
        LDS_FENCE();
    }
}

extern "C" void kernel_launch(void* const* d_in, const int* in_sizes, int n_in,
                              void* d_out, int out_size, void* d_ws, size_t ws_size,
                              hipStream_t stream) {
    const float* x      = (const float*)d_in[0];
    const float* conv_w = (const float*)d_in[1];
    const float* conv_b = (const float*)d_in[2];
    const float* gn_w   = (const float*)d_in[3];
    const float* gn_b   = (const float*)d_in[4];
    float* out = (float*)d_out;

    // ws: attn bf16 padded | rowAgg f32 | xT bf16 | wbf bf16
    ushort_t* attn    = (ushort_t*)d_ws;                    // 8,847,360 ushorts
    float*    rowAgg  = (float*)(attn + 8847360);           // 61,440 floats
    ushort_t* xT      = (ushort_t*)(rowAgg + 61440);        // 2,097,152 ushorts
    ushort_t* wbf     = xT + 2097152;                       // 196,608 ushorts

    prep<<<608, 256, 0, stream>>>(x, conv_w, xT, wbf);
    conv_gemm<<<dim3(128, 12), 256, 0, stream>>>(wbf, xT, conv_b, attn, rowAgg);
    local_attn<<<1024, 128, 0, stream>>>(attn, rowAgg, gn_w, gn_b, out);
}

// Round 7
// 108.955 us; speedup vs baseline: 1.8595x; 1.0030x over previous
//
#include <hip/hip_runtime.h>
#include <hip/hip_bf16.h>

#define B_    8
#define CIN   256
#define COUT  768
#define G_    24
#define PW    40         // padded row width (16B-aligned rows)
#define PLANE 1440       // 40*36
#define EPS_  1e-5f

typedef float f32x4 __attribute__((ext_vector_type(4)));
typedef short s16x8 __attribute__((ext_vector_type(8)));
typedef unsigned short ushort_t;
typedef unsigned short u16x4 __attribute__((ext_vector_type(4)));
typedef unsigned long long ull_t;

typedef const __attribute__((address_space(1))) void* gas_ptr_t;
typedef __attribute__((address_space(3))) void* las_ptr_t;

// LDS-only fence: compiler reordering barrier + s_waitcnt lgkmcnt(0).
// Does NOT wait vmcnt -> global prefetch loads stay in flight.
#define LDS_FENCE() do { asm volatile("" ::: "memory"); \
                         __builtin_amdgcn_s_waitcnt(0xC07F); \
                         asm volatile("" ::: "memory"); } while (0)

static __device__ __forceinline__ ushort_t f2bf(float f) {
    union { float f; unsigned u; } a; a.f = f;
    const unsigned u = a.u;
    const unsigned r = u + 0x7FFFu + ((u >> 16) & 1u);
    return (ushort_t)(r >> 16);
}
static __device__ __forceinline__ float bf2f(ushort_t h) {
    union { unsigned u; float f; } a; a.u = ((unsigned)h) << 16; return a.f;
}
static __device__ __forceinline__ void st4(float* dst, u16x4 v) {
    *(f32x4*)dst = f32x4{ bf2f(v[0]), bf2f(v[1]), bf2f(v[2]), bf2f(v[3]) };
}
static __device__ __forceinline__ unsigned pk2(float lo, float hi) {
    return (unsigned)f2bf(lo) | ((unsigned)f2bf(hi) << 16);
}

// ---------------- Kernel 0: one-time prep --------------------------------
__launch_bounds__(256)
__global__ void prep(const float* __restrict__ x, const float* __restrict__ wsrc,
                     ushort_t* __restrict__ xT, ushort_t* __restrict__ wbf) {
    const int bid = blockIdx.x;
    const int t = threadIdx.x;
    if (bid < 512) {
        const int nt = bid & 15, kt = (bid >> 4) & 3, b = bid >> 6;
        const int n0 = nt * 64, k0 = kt * 64;
        __shared__ float Ts[64][65];     // +1 pad: column reads 2-way free
        const int kr = t >> 2, c4 = t & 3;
        const float* src = x + (size_t)b * (CIN * 1024) + (size_t)(k0 + kr) * 1024 + n0 + c4 * 16;
        const float4 v0 = *(const float4*)(src + 0);
        const float4 v1 = *(const float4*)(src + 4);
        const float4 v2 = *(const float4*)(src + 8);
        const float4 v3 = *(const float4*)(src + 12);
        float* d = &Ts[kr][c4 * 16];
        *(float4*)(d + 0) = v0; *(float4*)(d + 4) = v1;
        *(float4*)(d + 8) = v2; *(float4*)(d + 12) = v3;
        __syncthreads();
        const int nr = t >> 2, k4 = t & 3;
        unsigned pk[8];
        #pragma unroll
        for (int i = 0; i < 8; ++i)
            pk[i] = pk2(Ts[k4 * 16 + 2 * i][nr], Ts[k4 * 16 + 2 * i + 1][nr]);
        ushort_t* dst = xT + (size_t)b * (1024 * 256) + (size_t)(n0 + nr) * 256 + k0 + k4 * 16;
        *(uint4*)(dst + 0) = uint4{ pk[0], pk[1], pk[2], pk[3] };
        *(uint4*)(dst + 8) = uint4{ pk[4], pk[5], pk[6], pk[7] };
    } else {
        const int wid = bid - 512;       // 96 blocks x 2048 elems
        const size_t idx = (size_t)wid * 2048 + (size_t)t * 8;
        const float4 u0 = *(const float4*)(wsrc + idx);
        const float4 u1 = *(const float4*)(wsrc + idx + 4);
        uint4 o;
        o.x = pk2(u0.x, u0.y); o.y = pk2(u0.z, u0.w);
        o.z = pk2(u1.x, u1.y); o.w = pk2(u1.z, u1.w);
        *(uint4*)(wbf + idx) = o;
    }
}

// ---------------- Kernel 1: bf16 MFMA GEMM -> attn + rowAgg ------------------
// (unchanged from R6: global_load_lds stage, flat source-swizzled LDS)
__launch_bounds__(256)
__global__ void conv_gemm(const ushort_t* __restrict__ wbf, const ushort_t* __restrict__ xT,
                          const float* __restrict__ bias, ushort_t* __restrict__ attn,
                          float* __restrict__ rowAgg) {
    const int t = threadIdx.x;
    const int wv = t >> 6, lane = t & 63;
    const int q = lane >> 4, l15 = lane & 15;
    const int m0 = blockIdx.y * 64;
    const int mw = wv * 16;
    const int n_t = blockIdx.x * 64;
    const int b = n_t >> 10, nl0 = n_t & 1023;
    const int y0 = nl0 >> 5;

    __shared__ ushort_t Bs[16384];       // flat [row][k] bf16, 32768 B
    ushort_t (*Ct)[2][44] = (ushort_t (*)[2][44])(&Bs[0]);
    float (*red)[11]      = (float (*)[11])((char*)(&Bs[0]) + 64 * 2 * 44 * 2);

    {
        const ushort_t* src = xT + (size_t)b * (1024 * 256) + (size_t)nl0 * 256;
        #pragma unroll
        for (int i = 0; i < 8; ++i) {
            const int idx = i * 256 + t;          // 16B chunk index 0..2047
            const int row = idx >> 5, s = idx & 31;
            const ushort_t* gp = src + row * 256 + ((s ^ (row & 7)) << 3);
            __builtin_amdgcn_global_load_lds((gas_ptr_t)gp, (las_ptr_t)&Bs[idx * 8],
                                             16, 0, 0);
        }
    }
    __syncthreads();   // drains vmcnt -> Bs ready

    const ushort_t* aPf = wbf + (size_t)(m0 + mw + l15) * 256 + q * 8;
    const int e7 = l15 & 7;

    f32x4 acc[4] = {{0,0,0,0},{0,0,0,0},{0,0,0,0},{0,0,0,0}};
    #pragma unroll
    for (int k0 = 0; k0 < 256; k0 += 32) {
        const s16x8 a = *(const s16x8*)(aPf + k0);
        const int sx = ((k0 >> 3) + q) ^ e7;      // swizzled 16B chunk index
        const ushort_t* bp = &Bs[l15 * 256 + sx * 8];
        const s16x8 b0 = *(const s16x8*)(bp +  0 * 256);
        const s16x8 b1 = *(const s16x8*)(bp + 16 * 256);
        const s16x8 b2 = *(const s16x8*)(bp + 32 * 256);
        const s16x8 b3 = *(const s16x8*)(bp + 48 * 256);
        acc[0] = __builtin_amdgcn_mfma_f32_16x16x32_bf16(a, b0, acc[0], 0, 0, 0);
        acc[1] = __builtin_amdgcn_mfma_f32_16x16x32_bf16(a, b1, acc[1], 0, 0, 0);
        acc[2] = __builtin_amdgcn_mfma_f32_16x16x32_bf16(a, b2, acc[2], 0, 0, 0);
        acc[3] = __builtin_amdgcn_mfma_f32_16x16x32_bf16(a, b3, acc[3], 0, 0, 0);
    }
    __syncthreads();   // Bs dead; Ct/red aliasing begins

    float bb[4];
    #pragma unroll
    for (int r = 0; r < 4; ++r) bb[r] = bias[m0 + mw + q * 4 + r];
    #pragma unroll
    for (int j = 0; j < 4; ++j) {
        const int yy = j >> 1, xx = (j & 1) * 16 + l15;
        #pragma unroll
        for (int r = 0; r < 4; ++r)
            Ct[mw + q * 4 + r][yy][2 + xx] = f2bf(acc[j][r] + bb[r]);
    }
    #pragma unroll
    for (int it = 0; it < 2; ++it) {
        const int id = it * 256 + t;
        const int m = id >> 3, yy = (id >> 2) & 1, pos = id & 3;
        const int us = (pos == 0) ? 0 : (32 + 2 * pos);
        *(unsigned*)&Ct[m][yy][us] = 0u;
    }
    __syncthreads();

    ushort_t* pb = attn + ((size_t)(b * COUT + m0)) * PLANE;
    #pragma unroll
    for (int it = 0; it < 5; ++it) {
        const int id = it * 256 + t;
        const int m = id / 20, rem = id % 20, yy = rem / 10, s = rem % 10;
        const ull_t v = *(const ull_t*)&Ct[m][yy][s * 4];
        *(ull_t*)(pb + (size_t)m * PLANE + (y0 + yy + 2) * PW + s * 4) = v;
    }
    if (y0 == 0 || y0 == 30) {
        const int rowA = (y0 == 0) ? 0 : 34;
        #pragma unroll
        for (int it = 0; it < 5; ++it) {
            const int id = it * 256 + t;
            const int m = id / 20, rem = id % 20, yy = rem / 10, s = rem % 10;
            *(ull_t*)(pb + (size_t)m * PLANE + (rowA + yy) * PW + s * 4) = 0ull;
        }
    }

    if (t < 128) {
        const int gi = t >> 6, yy = (t >> 5) & 1, c = t & 31;
        const int m = gi * 32 + c;
        float lin = 0.f, sq = 0.f, e0 = 0.f, e1 = 0.f, e30 = 0.f, e31 = 0.f;
        #pragma unroll
        for (int u = 0; u < 9; ++u) {
            const ull_t vv = *(const ull_t*)&Ct[m][yy][u * 4];
            const unsigned lo = (unsigned)vv, hi = (unsigned)(vv >> 32);
            union { unsigned u; float f; } f0, f1, f2, f3;
            f0.u = lo << 16; f1.u = lo & 0xffff0000u;
            f2.u = hi << 16; f3.u = hi & 0xffff0000u;
            lin += (f0.f + f1.f) + (f2.f + f3.f);
            sq  += (f0.f * f0.f + f1.f * f1.f) + (f2.f * f2.f + f3.f * f3.f);
            if (u == 0) { e0 = f2.f; e1 = f3.f; }
            if (u == 8) { e30 = f0.f; e31 = f1.f; }
        }
        red[t][0] = lin; red[t][1] = sq;
        red[t][2] = e0;  red[t][3] = e0 * e0;
        red[t][4] = e1;  red[t][5] = e1 * e1;
        red[t][6] = e30; red[t][7] = e30 * e30;
        red[t][8] = e31; red[t][9] = e31 * e31;
    }
    __syncthreads();
    if (t < 40) {
        const int s = t % 10, gy = t / 10;
        const int gi = gy >> 1, yy = gy & 1;
        float sum = 0.f;
        #pragma unroll
        for (int c = 0; c < 32; ++c) sum += red[gi * 64 + yy * 32 + c][s];
        const int g = blockIdx.y * 2 + gi;
        rowAgg[(((size_t)b * G_ + g) * 32 + (y0 + yy)) * 10 + s] = sum;
    }
}

// ---------------- Kernel 2: local attention — 2-wave blocks, 2-row slabs.
// R6 structure + two latency fixes:
//  (a) initial K/Q plane loads (plane 0 + ring 1..4) issue BEFORE the gnfin
//      phases -> ~1000 cy of stats compute covers the first-load latency;
//  (b) ring-of-4 register prefetch in ROLLED loops (#pragma unroll 2 only —
//      R4's full unroll spilled @256 VGPR). QK ring tail rotates V0..V7 in,
//      so the PV loop starts 7 planes deep and loads V8..V15 at cc=0..7. ----
__launch_bounds__(128)
__global__ void local_attn(const ushort_t* __restrict__ attn,
                           const float* __restrict__ rowAgg,
                           const float* __restrict__ gn_w, const float* __restrict__ gn_b,
                           float* __restrict__ out) {
    const int wid = blockIdx.x;          // 1024 = b(8) x n(8) x slab(16)
    const int b = wid >> 7;
    const int n = (wid >> 4) & 7;
    const int i0 = (wid & 15) * 2;       // first image row of the 2-row slab
    const int t = threadIdx.x;           // 128
    const int h = t >> 6;                // wave index = channel half
    const int lane = t & 63;
    const int r = lane >> 5;             // row within slab
    const int j = lane & 31;             // pixel column

    __shared__ float KB[2][2][240];      // [half][buf][6 rows x 40]
    __shared__ float QB[2][2][240];
    __shared__ float ex[128][27];        // sal exchange, stride-27 conflict-free
    __shared__ float rpL[96][5], rp2L[96][5];
    __shared__ float s_m[75], s_r[75];
    __shared__ float s_rq[25], s_mq[25], s_rk[25], s_ck[25], s_rv[25], s_cv[25];
    __shared__ float s_gw[96], s_gb[96];

    // ---- staging bases + EARLY issue of plane 0..4 loads (cover: gnfin) ----
    const ushort_t* regB = attn + (size_t)(b * COUT + n * 96) * PLANE + i0 * PW;
    const bool stg = (lane < 60);
    const int eo = lane * 4;
    const int base = r * PW + j;
    const ushort_t* baseK = regB + (size_t)(h * 16) * PLANE;
    const ushort_t* baseQ = regB + (size_t)(32 + h * 16) * PLANE;
    const ushort_t* baseV = regB + (size_t)(64 + h * 16) * PLANE;

    u16x4 c0K{0,0,0,0}, c0Q{0,0,0,0};
    u16x4 k1{0,0,0,0}, k2{0,0,0,0}, k3{0,0,0,0}, k4{0,0,0,0};
    u16x4 q1{0,0,0,0}, q2{0,0,0,0}, q3{0,0,0,0}, q4{0,0,0,0};
    if (stg) {
        c0K = *(const u16x4*)(baseK + eo);
        c0Q = *(const u16x4*)(baseQ + eo);
        k1 = *(const u16x4*)(baseK + 1 * (size_t)PLANE + eo);
        q1 = *(const u16x4*)(baseQ + 1 * (size_t)PLANE + eo);
        k2 = *(const u16x4*)(baseK + 2 * (size_t)PLANE + eo);
        q2 = *(const u16x4*)(baseQ + 2 * (size_t)PLANE + eo);
        k3 = *(const u16x4*)(baseK + 3 * (size_t)PLANE + eo);
        q3 = *(const u16x4*)(baseQ + 3 * (size_t)PLANE + eo);
        k4 = *(const u16x4*)(baseK + 4 * (size_t)PLANE + eo);
        q4 = *(const u16x4*)(baseQ + 4 * (size_t)PLANE + eo);
    }

    if (t < 96) { s_gw[t] = gn_w[n * 96 + t]; s_gb[t] = gn_b[n * 96 + t]; }

    // ---- fused gnfin, phase 1: per-(group,row) window column sums ----------
    const float* rab = rowAgg + (size_t)((b * G_ + n * 3) * 32) * 10;
    if (t < 96) {
        const float* a = rab + (size_t)t * 10;
        const float S = a[0], Sq = a[1];
        const float e0 = a[2], q0 = a[3], e1 = a[4], q1v = a[5];
        const float e30 = a[6], q30 = a[7], e31 = a[8], q31 = a[9];
        rpL[t][0] = S - e30 - e31; rpL[t][1] = S - e31; rpL[t][2] = S;
        rpL[t][3] = S - e0;        rpL[t][4] = S - e0 - e1;
        rp2L[t][0] = Sq - q30 - q31; rp2L[t][1] = Sq - q31; rp2L[t][2] = Sq;
        rp2L[t][3] = Sq - q0;        rp2L[t][4] = Sq - q0 - q1v;
    }
    __syncthreads();

    // ---- fused gnfin, phase 2: 75 (group,window) mean/rstd entries ---------
    if (t < 75) {
        const int gi = t / 25, p = t % 25;
        const int kw = p % 5, kh = p / 5;
        const int rb = gi * 32;
        float cs = 0.f, cs2 = 0.f;
        #pragma unroll
        for (int yy = 0; yy < 32; ++yy) { cs += rpL[rb + yy][kw]; cs2 += rp2L[rb + yy][kw]; }
        if (kh == 0)      { cs -= rpL[rb + 30][kw] + rpL[rb + 31][kw]; cs2 -= rp2L[rb + 30][kw] + rp2L[rb + 31][kw]; }
        else if (kh == 1) { cs -= rpL[rb + 31][kw];                    cs2 -= rp2L[rb + 31][kw]; }
        else if (kh == 3) { cs -= rpL[rb + 0][kw];                     cs2 -= rp2L[rb + 0][kw]; }
        else if (kh == 4) { cs -= rpL[rb + 0][kw] + rpL[rb + 1][kw];   cs2 -= rp2L[rb + 0][kw] + rp2L[rb + 1][kw]; }
        const float inv_n = 1.f / 32768.f;
        const float mean = cs * inv_n;
        const float var  = cs2 * inv_n - mean * mean;
        s_m[t] = mean;
        s_r[t] = rsqrtf(var + EPS_);
    }
    __syncthreads();

    if (t < 25) {
        const float mK = s_m[t],      rK = s_r[t];
        const float mQ = s_m[25 + t], rQ = s_r[25 + t];
        const float mV = s_m[50 + t], rV = s_r[50 + t];
        s_rk[t] = rK; s_ck[t] = mK * rK;
        s_rq[t] = rQ; s_mq[t] = mQ * rQ;
        s_rv[t] = rV; s_cv[t] = mV * rV;
    }
    __syncthreads();

    float rq[25]; float cQ = 0.f;
    #pragma unroll
    for (int p = 0; p < 25; ++p) { rq[p] = s_rq[p]; cQ += s_mq[p]; }

    if (stg) {
        st4(&KB[h][0][eo], c0K);
        st4(&QB[h][0][eo], c0Q);
    }
    LDS_FENCE();

    float sal[25];
    #pragma unroll
    for (int p = 0; p < 25; ++p) sal[p] = 0.f;
    float sumQ2 = 0.f, sumQB = 0.f;

    #pragma unroll 2
    for (int cc = 0; cc < 16; ++cc) {
        const int buf = cc & 1;
        if (stg && cc < 15) {
            st4(&KB[h][buf ^ 1][eo], k1);     // plane cc+1
            st4(&QB[h][buf ^ 1][eo], q1);
            k1 = k2; k2 = k3; k3 = k4;
            q1 = q2; q2 = q3; q3 = q4;
            if (cc < 11) {                    // K/Q plane cc+5
                k4 = *(const u16x4*)(baseK + (size_t)(cc + 5) * PLANE + eo);
                q4 = *(const u16x4*)(baseQ + (size_t)(cc + 5) * PLANE + eo);
            } else {                          // tail: V0..V3 and V4..V7
                k4 = *(const u16x4*)(baseV + (size_t)(cc - 11) * PLANE + eo);
                q4 = *(const u16x4*)(baseV + (size_t)(cc - 7) * PLANE + eo);
            }
        }
        const int ch = h * 16 + cc;
        const float* qb = &QB[h][buf][base];
        const float* kb = &KB[h][buf][base];
        float qa0 = 0.f, qa1 = 0.f, qa2 = 0.f, qa3 = 0.f, qa4 = 0.f;
        #pragma unroll
        for (int kw = 0; kw < 5; ++kw) {
            qa0 += rq[0 * 5 + kw] * qb[0 * PW + kw];
            qa1 += rq[1 * 5 + kw] * qb[1 * PW + kw];
            qa2 += rq[2 * 5 + kw] * qb[2 * PW + kw];
            qa3 += rq[3 * 5 + kw] * qb[3 * PW + kw];
            qa4 += rq[4 * 5 + kw] * qb[4 * PW + kw];
        }
        const float qa = (qa0 + qa1) + (qa2 + qa3) + qa4;
        const float qk  = s_gw[32 + ch] * ((qa - cQ) * 0.04f) + s_gb[32 + ch];
        const float qk2 = qk * s_gw[ch];
        sumQ2 += qk2; sumQB += qk * s_gb[ch];
        #pragma unroll
        for (int kh = 0; kh < 5; ++kh)
            #pragma unroll
            for (int kw = 0; kw < 5; ++kw)
                sal[kh * 5 + kw] += qk2 * kb[kh * PW + kw];
        LDS_FENCE();
    }
    // ring now holds V planes: k1..k4 = V0..V3, q1..q4 = V4..V7

    // cross-wave exchange (lane t <-> t^64): write partials + stage V0, barrier
    #pragma unroll
    for (int p = 0; p < 25; ++p) ex[t][p] = sal[p];
    ex[t][25] = sumQ2; ex[t][26] = sumQB;
    if (stg) st4(&KB[h][0][eo], k1);     // V0 -> buf0 (wave-private)
    __syncthreads();
    const int par = t ^ 64;
    #pragma unroll
    for (int p = 0; p < 25; ++p) sal[p] += ex[par][p];
    sumQ2 += ex[par][25]; sumQB += ex[par][26];

    #pragma unroll
    for (int p = 0; p < 25; ++p) sal[p] = s_rk[p] * sal[p] - s_ck[p] * sumQ2 + sumQB;

    const float scale = 0.17677669529663687f;  // 1/sqrt(32)
    float mmax = -3.4e38f;
    #pragma unroll
    for (int p = 0; p < 25; ++p) { sal[p] *= scale; mmax = fmaxf(mmax, sal[p]); }
    float ssum = 0.f;
    #pragma unroll
    for (int p = 0; p < 25; ++p) { sal[p] = __expf(sal[p] - mmax); ssum += sal[p]; }
    const float rs = 1.f / ssum;
    float cV2 = 0.f;
    #pragma unroll
    for (int p = 0; p < 25; ++p) {
        const float m = sal[p] * rs;
        sal[p] = m * s_rv[p];        // reuse sal as V-tap weights
        cV2 += m * s_cv[p];
    }
    LDS_FENCE();

    // PV ring: k2,k3,k4,q1..q4 = V1..V7; loads at cc=0..7 fetch V8..V15
    #pragma unroll 2
    for (int cc = 0; cc < 16; ++cc) {
        const int buf = cc & 1;
        if (stg && cc < 15) {
            st4(&KB[h][buf ^ 1][eo], k2);     // V(cc+1)
            k2 = k3; k3 = k4; k4 = q1; q1 = q2; q2 = q3; q3 = q4;
            if (cc < 8)
                q4 = *(const u16x4*)(baseV + (size_t)(cc + 8) * PLANE + eo);
        }
        const int v = h * 16 + cc;
        const float* vb = &KB[h][buf][base];
        float a0 = 0.f, a1 = 0.f, a2 = 0.f, a3 = 0.f, a4 = 0.f;
        #pragma unroll
        for (int kw = 0; kw < 5; ++kw) {
            a0 += sal[0 * 5 + kw] * vb[0 * PW + kw];
            a1 += sal[1 * 5 + kw] * vb[1 * PW + kw];
            a2 += sal[2 * 5 + kw] * vb[2 * PW + kw];
            a3 += sal[3 * 5 + kw] * vb[3 * PW + kw];
            a4 += sal[4 * 5 + kw] * vb[4 * PW + kw];
        }
        const float acc = (a0 + a1) + (a2 + a3) + a4;
        out[((size_t)(b * 256 + n * 32 + v) * 32 + (i0 + r)) * 32 + j] =
            s_gw[64 + v] * acc + (s_gb[64 + v] - s_gw[64 + v] * cV2);
        LDS_FENCE();
    }
}

extern "C" void kernel_launch(void* const* d_in, const int* in_sizes, int n_in,
                              void* d_out, int out_size, void* d_ws, size_t ws_size,
                              hipStream_t stream) {
    const float* x      = (const float*)d_in[0];
    const float* conv_w = (const float*)d_in[1];
    const float* conv_b = (const float*)d_in[2];
    const float* gn_w   = (const float*)d_in[3];
    const float* gn_b   = (const float*)d_in[4];
    float* out = (float*)d_out;

    // ws: attn bf16 padded | rowAgg f32 | xT bf16 | wbf bf16
    ushort_t* attn    = (ushort_t*)d_ws;                    // 8,847,360 ushorts
    float*    rowAgg  = (float*)(attn + 8847360);           // 61,440 floats
    ushort_t* xT      = (ushort_t*)(rowAgg + 61440);        // 2,097,152 ushorts
    ushort_t* wbf     = xT + 2097152;                       // 196,608 ushorts

    prep<<<608, 256, 0, stream>>>(x, conv_w, xT, wbf);
    conv_gemm<<<dim3(128, 12), 256, 0, stream>>>(wbf, xT, conv_b, attn, rowAgg);
    local_attn<<<1024, 128, 0, stream>>>(attn, rowAgg, gn_w, gn_b, out);
}

// Round 8
// 107.786 us; speedup vs baseline: 1.8797x; 1.0108x over previous
//
#include <hip/hip_runtime.h>
#include <hip/hip_bf16.h>

#define B_    8
#define CIN   256
#define COUT  768
#define G_    24
#define PW    40         // padded row width (16B-aligned rows)
#define PLANE 1440       // 40*36
#define EPS_  1e-5f

typedef float f32x4 __attribute__((ext_vector_type(4)));
typedef short s16x8 __attribute__((ext_vector_type(8)));
typedef unsigned short ushort_t;
typedef unsigned short u16x4 __attribute__((ext_vector_type(4)));
typedef unsigned long long ull_t;

typedef const __attribute__((address_space(1))) void* gas_ptr_t;
typedef __attribute__((address_space(3))) void* las_ptr_t;

// LDS-only fence: compiler reordering barrier + s_waitcnt lgkmcnt(0).
// Does NOT wait vmcnt -> global prefetch loads stay in flight.
#define LDS_FENCE() do { asm volatile("" ::: "memory"); \
                         __builtin_amdgcn_s_waitcnt(0xC07F); \
                         asm volatile("" ::: "memory"); } while (0)

static __device__ __forceinline__ ushort_t f2bf(float f) {
    union { float f; unsigned u; } a; a.f = f;
    const unsigned u = a.u;
    const unsigned r = u + 0x7FFFu + ((u >> 16) & 1u);
    return (ushort_t)(r >> 16);
}
static __device__ __forceinline__ float bf2f(ushort_t h) {
    union { unsigned u; float f; } a; a.u = ((unsigned)h) << 16; return a.f;
}
// interleaved pair store: dst[0,2,4,6] = a, dst[1,3,5,7] = b  (two b128 writes)
static __device__ __forceinline__ void st4p(float* dst, u16x4 a, u16x4 b) {
    *(f32x4*)(dst + 0) = f32x4{ bf2f(a[0]), bf2f(b[0]), bf2f(a[1]), bf2f(b[1]) };
    *(f32x4*)(dst + 4) = f32x4{ bf2f(a[2]), bf2f(b[2]), bf2f(a[3]), bf2f(b[3]) };
}
static __device__ __forceinline__ unsigned pk2(float lo, float hi) {
    return (unsigned)f2bf(lo) | ((unsigned)f2bf(hi) << 16);
}

// ---------------- Kernel 0: one-time prep --------------------------------
__launch_bounds__(256)
__global__ void prep(const float* __restrict__ x, const float* __restrict__ wsrc,
                     ushort_t* __restrict__ xT, ushort_t* __restrict__ wbf) {
    const int bid = blockIdx.x;
    const int t = threadIdx.x;
    if (bid < 512) {
        const int nt = bid & 15, kt = (bid >> 4) & 3, b = bid >> 6;
        const int n0 = nt * 64, k0 = kt * 64;
        __shared__ float Ts[64][65];     // +1 pad: column reads 2-way free
        const int kr = t >> 2, c4 = t & 3;
        const float* src = x + (size_t)b * (CIN * 1024) + (size_t)(k0 + kr) * 1024 + n0 + c4 * 16;
        const float4 v0 = *(const float4*)(src + 0);
        const float4 v1 = *(const float4*)(src + 4);
        const float4 v2 = *(const float4*)(src + 8);
        const float4 v3 = *(const float4*)(src + 12);
        float* d = &Ts[kr][c4 * 16];
        *(float4*)(d + 0) = v0; *(float4*)(d + 4) = v1;
        *(float4*)(d + 8) = v2; *(float4*)(d + 12) = v3;
        __syncthreads();
        const int nr = t >> 2, k4 = t & 3;
        unsigned pk[8];
        #pragma unroll
        for (int i = 0; i < 8; ++i)
            pk[i] = pk2(Ts[k4 * 16 + 2 * i][nr], Ts[k4 * 16 + 2 * i + 1][nr]);
        ushort_t* dst = xT + (size_t)b * (1024 * 256) + (size_t)(n0 + nr) * 256 + k0 + k4 * 16;
        *(uint4*)(dst + 0) = uint4{ pk[0], pk[1], pk[2], pk[3] };
        *(uint4*)(dst + 8) = uint4{ pk[4], pk[5], pk[6], pk[7] };
    } else {
        const int wid = bid - 512;       // 96 blocks x 2048 elems
        const size_t idx = (size_t)wid * 2048 + (size_t)t * 8;
        const float4 u0 = *(const float4*)(wsrc + idx);
        const float4 u1 = *(const float4*)(wsrc + idx + 4);
        uint4 o;
        o.x = pk2(u0.x, u0.y); o.y = pk2(u0.z, u0.w);
        o.z = pk2(u1.x, u1.y); o.w = pk2(u1.z, u1.w);
        *(uint4*)(wbf + idx) = o;
    }
}

// ---------------- Kernel 1: bf16 MFMA GEMM -> attn + rowAgg ------------------
// (unchanged from R6: global_load_lds stage, flat source-swizzled LDS)
__launch_bounds__(256)
__global__ void conv_gemm(const ushort_t* __restrict__ wbf, const ushort_t* __restrict__ xT,
                          const float* __restrict__ bias, ushort_t* __restrict__ attn,
                          float* __restrict__ rowAgg) {
    const int t = threadIdx.x;
    const int wv = t >> 6, lane = t & 63;
    const int q = lane >> 4, l15 = lane & 15;
    const int m0 = blockIdx.y * 64;
    const int mw = wv * 16;
    const int n_t = blockIdx.x * 64;
    const int b = n_t >> 10, nl0 = n_t & 1023;
    const int y0 = nl0 >> 5;

    __shared__ ushort_t Bs[16384];       // flat [row][k] bf16, 32768 B
    ushort_t (*Ct)[2][44] = (ushort_t (*)[2][44])(&Bs[0]);
    float (*red)[11]      = (float (*)[11])((char*)(&Bs[0]) + 64 * 2 * 44 * 2);

    {
        const ushort_t* src = xT + (size_t)b * (1024 * 256) + (size_t)nl0 * 256;
        #pragma unroll
        for (int i = 0; i < 8; ++i) {
            const int idx = i * 256 + t;          // 16B chunk index 0..2047
            const int row = idx >> 5, s = idx & 31;
            const ushort_t* gp = src + row * 256 + ((s ^ (row & 7)) << 3);
            __builtin_amdgcn_global_load_lds((gas_ptr_t)gp, (las_ptr_t)&Bs[idx * 8],
                                             16, 0, 0);
        }
    }
    __syncthreads();   // drains vmcnt -> Bs ready

    const ushort_t* aPf = wbf + (size_t)(m0 + mw + l15) * 256 + q * 8;
    const int e7 = l15 & 7;

    f32x4 acc[4] = {{0,0,0,0},{0,0,0,0},{0,0,0,0},{0,0,0,0}};
    #pragma unroll
    for (int k0 = 0; k0 < 256; k0 += 32) {
        const s16x8 a = *(const s16x8*)(aPf + k0);
        const int sx = ((k0 >> 3) + q) ^ e7;      // swizzled 16B chunk index
        const ushort_t* bp = &Bs[l15 * 256 + sx * 8];
        const s16x8 b0 = *(const s16x8*)(bp +  0 * 256);
        const s16x8 b1 = *(const s16x8*)(bp + 16 * 256);
        const s16x8 b2 = *(const s16x8*)(bp + 32 * 256);
        const s16x8 b3 = *(const s16x8*)(bp + 48 * 256);
        acc[0] = __builtin_amdgcn_mfma_f32_16x16x32_bf16(a, b0, acc[0], 0, 0, 0);
        acc[1] = __builtin_amdgcn_mfma_f32_16x16x32_bf16(a, b1, acc[1], 0, 0, 0);
        acc[2] = __builtin_amdgcn_mfma_f32_16x16x32_bf16(a, b2, acc[2], 0, 0, 0);
        acc[3] = __builtin_amdgcn_mfma_f32_16x16x32_bf16(a, b3, acc[3], 0, 0, 0);
    }
    __syncthreads();   // Bs dead; Ct/red aliasing begins

    float bb[4];
    #pragma unroll
    for (int r = 0; r < 4; ++r) bb[r] = bias[m0 + mw + q * 4 + r];
    #pragma unroll
    for (int j = 0; j < 4; ++j) {
        const int yy = j >> 1, xx = (j & 1) * 16 + l15;
        #pragma unroll
        for (int r = 0; r < 4; ++r)
            Ct[mw + q * 4 + r][yy][2 + xx] = f2bf(acc[j][r] + bb[r]);
    }
    #pragma unroll
    for (int it = 0; it < 2; ++it) {
        const int id = it * 256 + t;
        const int m = id >> 3, yy = (id >> 2) & 1, pos = id & 3;
        const int us = (pos == 0) ? 0 : (32 + 2 * pos);
        *(unsigned*)&Ct[m][yy][us] = 0u;
    }
    __syncthreads();

    ushort_t* pb = attn + ((size_t)(b * COUT + m0)) * PLANE;
    #pragma unroll
    for (int it = 0; it < 5; ++it) {
        const int id = it * 256 + t;
        const int m = id / 20, rem = id % 20, yy = rem / 10, s = rem % 10;
        const ull_t v = *(const ull_t*)&Ct[m][yy][s * 4];
        *(ull_t*)(pb + (size_t)m * PLANE + (y0 + yy + 2) * PW + s * 4) = v;
    }
    if (y0 == 0 || y0 == 30) {
        const int rowA = (y0 == 0) ? 0 : 34;
        #pragma unroll
        for (int it = 0; it < 5; ++it) {
            const int id = it * 256 + t;
            const int m = id / 20, rem = id % 20, yy = rem / 10, s = rem % 10;
            *(ull_t*)(pb + (size_t)m * PLANE + (rowA + yy) * PW + s * 4) = 0ull;
        }
    }

    if (t < 128) {
        const int gi = t >> 6, yy = (t >> 5) & 1, c = t & 31;
        const int m = gi * 32 + c;
        float lin = 0.f, sq = 0.f, e0 = 0.f, e1 = 0.f, e30 = 0.f, e31 = 0.f;
        #pragma unroll
        for (int u = 0; u < 9; ++u) {
            const ull_t vv = *(const ull_t*)&Ct[m][yy][u * 4];
            const unsigned lo = (unsigned)vv, hi = (unsigned)(vv >> 32);
            union { unsigned u; float f; } f0, f1, f2, f3;
            f0.u = lo << 16; f1.u = lo & 0xffff0000u;
            f2.u = hi << 16; f3.u = hi & 0xffff0000u;
            lin += (f0.f + f1.f) + (f2.f + f3.f);
            sq  += (f0.f * f0.f + f1.f * f1.f) + (f2.f * f2.f + f3.f * f3.f);
            if (u == 0) { e0 = f2.f; e1 = f3.f; }
            if (u == 8) { e30 = f0.f; e31 = f1.f; }
        }
        red[t][0] = lin; red[t][1] = sq;
        red[t][2] = e0;  red[t][3] = e0 * e0;
        red[t][4] = e1;  red[t][5] = e1 * e1;
        red[t][6] = e30; red[t][7] = e30 * e30;
        red[t][8] = e31; red[t][9] = e31 * e31;
    }
    __syncthreads();
    if (t < 40) {
        const int s = t % 10, gy = t / 10;
        const int gi = gy >> 1, yy = gy & 1;
        float sum = 0.f;
        #pragma unroll
        for (int c = 0; c < 32; ++c) sum += red[gi * 64 + yy * 32 + c][s];
        const int g = blockIdx.y * 2 + gi;
        rowAgg[(((size_t)b * G_ + g) * 32 + (y0 + yy)) * 10 + s] = sum;
    }
}

// ---------------- Kernel 2: local attention — 2-wave blocks, 2-row slabs.
// LDS-instruction halving: K and Q planes stored ELEMENT-INTERLEAVED in one
// buffer -> one ds_read_b64 per tap serves both (25 reads vs 50; K parks in
// kv[25] until qk2 is ready). PV processes TWO V planes per iteration from
// the same interleaved layout (12.5 reads/plane; 8 iterations, 8 fences).
// All summation orders preserved element-for-element (bit-identical). -------
__launch_bounds__(128)
__global__ void local_attn(const ushort_t* __restrict__ attn,
                           const float* __restrict__ rowAgg,
                           const float* __restrict__ gn_w, const float* __restrict__ gn_b,
                           float* __restrict__ out) {
    const int wid = blockIdx.x;          // 1024 = b(8) x n(8) x slab(16)
    const int b = wid >> 7;
    const int n = (wid >> 4) & 7;
    const int i0 = (wid & 15) * 2;       // first image row of the 2-row slab
    const int t = threadIdx.x;           // 128
    const int h = t >> 6;                // wave index = channel half
    const int lane = t & 63;
    const int r = lane >> 5;             // row within slab
    const int j = lane & 31;             // pixel column

    __shared__ float PB[2][2][480];      // [half][buf][240 taps x pair(even=K/V_lo, odd=Q/V_hi)]
    __shared__ float ex[128][27];        // sal exchange, stride-27 conflict-free
    __shared__ float rpL[96][5], rp2L[96][5];
    __shared__ float s_m[75], s_r[75];
    __shared__ float s_rq[25], s_mq[25], s_rk[25], s_ck[25], s_rv[25], s_cv[25];
    __shared__ float s_gw[96], s_gb[96];

    // ---- staging bases + early issue of plane 0..2 loads (cover: gnfin) ----
    const ushort_t* regB = attn + (size_t)(b * COUT + n * 96) * PLANE + i0 * PW;
    const bool stg = (lane < 60);
    const int eo = lane * 4;
    const int b2 = 2 * (r * PW + j);     // word offset of this lane's window base
    const ushort_t* baseK = regB + (size_t)(h * 16) * PLANE;
    const ushort_t* baseQ = regB + (size_t)(32 + h * 16) * PLANE;
    const ushort_t* baseV = regB + (size_t)(64 + h * 16) * PLANE;

    u16x4 c0K{0,0,0,0}, c0Q{0,0,0,0};
    u16x4 nK{0,0,0,0}, nQ{0,0,0,0}, fK{0,0,0,0}, fQ{0,0,0,0};
    if (stg) {
        c0K = *(const u16x4*)(baseK + eo);
        c0Q = *(const u16x4*)(baseQ + eo);
        nK = *(const u16x4*)(baseK + (size_t)PLANE + eo);
        nQ = *(const u16x4*)(baseQ + (size_t)PLANE + eo);
        fK = *(const u16x4*)(baseK + 2 * (size_t)PLANE + eo);
        fQ = *(const u16x4*)(baseQ + 2 * (size_t)PLANE + eo);
    }

    if (t < 96) { s_gw[t] = gn_w[n * 96 + t]; s_gb[t] = gn_b[n * 96 + t]; }

    // ---- fused gnfin, phase 1: per-(group,row) window column sums ----------
    const float* rab = rowAgg + (size_t)((b * G_ + n * 3) * 32) * 10;
    if (t < 96) {
        const float* a = rab + (size_t)t * 10;
        const float S = a[0], Sq = a[1];
        const float e0 = a[2], q0 = a[3], e1 = a[4], q1v = a[5];
        const float e30 = a[6], q30 = a[7], e31 = a[8], q31 = a[9];
        rpL[t][0] = S - e30 - e31; rpL[t][1] = S - e31; rpL[t][2] = S;
        rpL[t][3] = S - e0;        rpL[t][4] = S - e0 - e1;
        rp2L[t][0] = Sq - q30 - q31; rp2L[t][1] = Sq - q31; rp2L[t][2] = Sq;
        rp2L[t][3] = Sq - q0;        rp2L[t][4] = Sq - q0 - q1v;
    }
    __syncthreads();

    // ---- fused gnfin, phase 2: 75 (group,window) mean/rstd entries ---------
    if (t < 75) {
        const int gi = t / 25, p = t % 25;
        const int kw = p % 5, kh = p / 5;
        const int rb = gi * 32;
        float cs = 0.f, cs2 = 0.f;
        #pragma unroll
        for (int yy = 0; yy < 32; ++yy) { cs += rpL[rb + yy][kw]; cs2 += rp2L[rb + yy][kw]; }
        if (kh == 0)      { cs -= rpL[rb + 30][kw] + rpL[rb + 31][kw]; cs2 -= rp2L[rb + 30][kw] + rp2L[rb + 31][kw]; }
        else if (kh == 1) { cs -= rpL[rb + 31][kw];                    cs2 -= rp2L[rb + 31][kw]; }
        else if (kh == 3) { cs -= rpL[rb + 0][kw];                     cs2 -= rp2L[rb + 0][kw]; }
        else if (kh == 4) { cs -= rpL[rb + 0][kw] + rpL[rb + 1][kw];   cs2 -= rp2L[rb + 0][kw] + rp2L[rb + 1][kw]; }
        const float inv_n = 1.f / 32768.f;
        const float mean = cs * inv_n;
        const float var  = cs2 * inv_n - mean * mean;
        s_m[t] = mean;
        s_r[t] = rsqrtf(var + EPS_);
    }
    __syncthreads();

    if (t < 25) {
        const float mK = s_m[t],      rK = s_r[t];
        const float mQ = s_m[25 + t], rQ = s_r[25 + t];
        const float mV = s_m[50 + t], rV = s_r[50 + t];
        s_rk[t] = rK; s_ck[t] = mK * rK;
        s_rq[t] = rQ; s_mq[t] = mQ * rQ;
        s_rv[t] = rV; s_cv[t] = mV * rV;
    }
    __syncthreads();

    float rq[25]; float cQ = 0.f;
    #pragma unroll
    for (int p = 0; p < 25; ++p) { rq[p] = s_rq[p]; cQ += s_mq[p]; }

    if (stg) st4p(&PB[h][0][2 * eo], c0K, c0Q);
    LDS_FENCE();

    float sal[25];
    #pragma unroll
    for (int p = 0; p < 25; ++p) sal[p] = 0.f;
    float sumQ2 = 0.f, sumQB = 0.f;

    #pragma unroll 2
    for (int cc = 0; cc < 16; ++cc) {
        const int buf = cc & 1;
        if (stg && cc < 15) {
            st4p(&PB[h][buf ^ 1][2 * eo], nK, nQ);    // plane cc+1 (K,Q interleaved)
            nK = fK; nQ = fQ;
            if (cc < 13) {                            // K/Q plane cc+3
                fK = *(const u16x4*)(baseK + (size_t)(cc + 3) * PLANE + eo);
                fQ = *(const u16x4*)(baseQ + (size_t)(cc + 3) * PLANE + eo);
            } else if (cc == 13) {                    // tail: V0,V1
                fK = *(const u16x4*)(baseV + eo);
                fQ = *(const u16x4*)(baseV + (size_t)PLANE + eo);
            } else {                                  // cc == 14: V2,V3
                fK = *(const u16x4*)(baseV + 2 * (size_t)PLANE + eo);
                fQ = *(const u16x4*)(baseV + 3 * (size_t)PLANE + eo);
            }
        }
        const int ch = h * 16 + cc;
        const float* pb = &PB[h][buf][0];
        float kv[25];
        float qa0 = 0.f, qa1 = 0.f, qa2 = 0.f, qa3 = 0.f, qa4 = 0.f;
        #pragma unroll
        for (int kw = 0; kw < 5; ++kw) {
            const float2 t0 = *(const float2*)&pb[b2 + 2 * (0 * PW + kw)];
            const float2 t1 = *(const float2*)&pb[b2 + 2 * (1 * PW + kw)];
            const float2 t2 = *(const float2*)&pb[b2 + 2 * (2 * PW + kw)];
            const float2 t3 = *(const float2*)&pb[b2 + 2 * (3 * PW + kw)];
            const float2 t4 = *(const float2*)&pb[b2 + 2 * (4 * PW + kw)];
            kv[0 * 5 + kw] = t0.x; qa0 += rq[0 * 5 + kw] * t0.y;
            kv[1 * 5 + kw] = t1.x; qa1 += rq[1 * 5 + kw] * t1.y;
            kv[2 * 5 + kw] = t2.x; qa2 += rq[2 * 5 + kw] * t2.y;
            kv[3 * 5 + kw] = t3.x; qa3 += rq[3 * 5 + kw] * t3.y;
            kv[4 * 5 + kw] = t4.x; qa4 += rq[4 * 5 + kw] * t4.y;
        }
        const float qa = (qa0 + qa1) + (qa2 + qa3) + qa4;
        const float qk  = s_gw[32 + ch] * ((qa - cQ) * 0.04f) + s_gb[32 + ch];
        const float qk2 = qk * s_gw[ch];
        sumQ2 += qk2; sumQB += qk * s_gb[ch];
        #pragma unroll
        for (int p = 0; p < 25; ++p) sal[p] += qk2 * kv[p];
        LDS_FENCE();
    }
    // exit: nK,nQ = V0,V1 ; fK,fQ = V2,V3

    // cross-wave exchange: write partials + stage V pair0, barrier
    #pragma unroll
    for (int p = 0; p < 25; ++p) ex[t][p] = sal[p];
    ex[t][25] = sumQ2; ex[t][26] = sumQB;
    if (stg) st4p(&PB[h][0][2 * eo], nK, nQ);   // pair0 = (V0,V1) -> buf0
    __syncthreads();
    const int par = t ^ 64;
    #pragma unroll
    for (int p = 0; p < 25; ++p) sal[p] += ex[par][p];
    sumQ2 += ex[par][25]; sumQB += ex[par][26];

    u16x4 vA0 = fK, vA1 = fQ;                    // pair1 = (V2,V3)
    u16x4 vB0{0,0,0,0}, vB1{0,0,0,0};
    if (stg) {                                   // pair2 = (V4,V5), post-barrier
        vB0 = *(const u16x4*)(baseV + 4 * (size_t)PLANE + eo);
        vB1 = *(const u16x4*)(baseV + 5 * (size_t)PLANE + eo);
    }

    #pragma unroll
    for (int p = 0; p < 25; ++p) sal[p] = s_rk[p] * sal[p] - s_ck[p] * sumQ2 + sumQB;

    const float scale = 0.17677669529663687f;  // 1/sqrt(32)
    float mmax = -3.4e38f;
    #pragma unroll
    for (int p = 0; p < 25; ++p) { sal[p] *= scale; mmax = fmaxf(mmax, sal[p]); }
    float ssum = 0.f;
    #pragma unroll
    for (int p = 0; p < 25; ++p) { sal[p] = __expf(sal[p] - mmax); ssum += sal[p]; }
    const float rs = 1.f / ssum;
    float cV2 = 0.f;
    #pragma unroll
    for (int p = 0; p < 25; ++p) {
        const float m = sal[p] * rs;
        sal[p] = m * s_rv[p];        // reuse sal as V-tap weights
        cV2 += m * s_cv[p];
    }
    LDS_FENCE();

    // PV: 8 iterations, TWO V planes each (pair vp from buf vp&1)
    #pragma unroll 2
    for (int vp = 0; vp < 8; ++vp) {
        const int buf = vp & 1;
        if (stg && vp < 7) {
            st4p(&PB[h][buf ^ 1][2 * eo], vA0, vA1);   // pair vp+1
            vA0 = vB0; vA1 = vB1;
            if (vp < 5) {                              // pair vp+3 = planes 2vp+6, 2vp+7
                vB0 = *(const u16x4*)(baseV + (size_t)(2 * vp + 6) * PLANE + eo);
                vB1 = *(const u16x4*)(baseV + (size_t)(2 * vp + 7) * PLANE + eo);
            }
        }
        const int v0 = h * 16 + 2 * vp;
        const float* pb = &PB[h][buf][0];
        float l0 = 0.f, l1 = 0.f, l2 = 0.f, l3 = 0.f, l4 = 0.f;
        float g0 = 0.f, g1 = 0.f, g2 = 0.f, g3 = 0.f, g4 = 0.f;
        #pragma unroll
        for (int kw = 0; kw < 5; ++kw) {
            const float2 t0 = *(const float2*)&pb[b2 + 2 * (0 * PW + kw)];
            const float2 t1 = *(const float2*)&pb[b2 + 2 * (1 * PW + kw)];
            const float2 t2 = *(const float2*)&pb[b2 + 2 * (2 * PW + kw)];
            const float2 t3 = *(const float2*)&pb[b2 + 2 * (3 * PW + kw)];
            const float2 t4 = *(const float2*)&pb[b2 + 2 * (4 * PW + kw)];
            l0 += sal[0 * 5 + kw] * t0.x; g0 += sal[0 * 5 + kw] * t0.y;
            l1 += sal[1 * 5 + kw] * t1.x; g1 += sal[1 * 5 + kw] * t1.y;
            l2 += sal[2 * 5 + kw] * t2.x; g2 += sal[2 * 5 + kw] * t2.y;
            l3 += sal[3 * 5 + kw] * t3.x; g3 += sal[3 * 5 + kw] * t3.y;
            l4 += sal[4 * 5 + kw] * t4.x; g4 += sal[4 * 5 + kw] * t4.y;
        }
        const float aL = (l0 + l1) + (l2 + l3) + l4;
        const float aH = (g0 + g1) + (g2 + g3) + g4;
        const size_t ob = ((size_t)(b * 256 + n * 32 + v0) * 32 + (i0 + r)) * 32 + j;
        out[ob]        = s_gw[64 + v0] * aL + (s_gb[64 + v0] - s_gw[64 + v0] * cV2);
        out[ob + 1024] = s_gw[65 + v0] * aH + (s_gb[65 + v0] - s_gw[65 + v0] * cV2);
        LDS_FENCE();
    }
}

extern "C" void kernel_launch(void* const* d_in, const int* in_sizes, int n_in,
                              void* d_out, int out_size, void* d_ws, size_t ws_size,
                              hipStream_t stream) {
    const float* x      = (const float*)d_in[0];
    const float* conv_w = (const float*)d_in[1];
    const float* conv_b = (const float*)d_in[2];
    const float* gn_w   = (const float*)d_in[3];
    const float* gn_b   = (const float*)d_in[4];
    float* out = (float*)d_out;

    // ws: attn bf16 padded | rowAgg f32 | xT bf16 | wbf bf16
    ushort_t* attn    = (ushort_t*)d_ws;                    // 8,847,360 ushorts
    float*    rowAgg  = (float*)(attn + 8847360);           // 61,440 floats
    ushort_t* xT      = (ushort_t*)(rowAgg + 61440);        // 2,097,152 ushorts
    ushort_t* wbf     = xT + 2097152;                       // 196,608 ushorts

    prep<<<608, 256, 0, stream>>>(x, conv_w, xT, wbf);
    conv_gemm<<<dim3(128, 12), 256, 0, stream>>>(wbf, xT, conv_b, attn, rowAgg);
    local_attn<<<1024, 128, 0, stream>>>(attn, rowAgg, gn_w, gn_b, out);
}

// Round 10
// 106.995 us; speedup vs baseline: 1.8936x; 1.0074x over previous
//
#include <hip/hip_runtime.h>
#include <hip/hip_bf16.h>

#define B_    8
#define CIN   256
#define COUT  768
#define G_    24
#define PW    40         // padded row width (16B-aligned rows)
#define PLANE 1440       // 40*36
#define EPS_  1e-5f

typedef float f32x4 __attribute__((ext_vector_type(4)));
typedef short s16x8 __attribute__((ext_vector_type(8)));
typedef unsigned short ushort_t;
typedef unsigned short u16x4 __attribute__((ext_vector_type(4)));
typedef unsigned long long ull_t;

typedef const __attribute__((address_space(1))) void* gas_ptr_t;
typedef __attribute__((address_space(3))) void* las_ptr_t;

// LDS-only fence: compiler reordering barrier + s_waitcnt lgkmcnt(0).
// Does NOT wait vmcnt -> global prefetch loads stay in flight.
#define LDS_FENCE() do { asm volatile("" ::: "memory"); \
                         __builtin_amdgcn_s_waitcnt(0xC07F); \
                         asm volatile("" ::: "memory"); } while (0)

// Counted-vmcnt barrier: wait until <=N of this wave's vmem ops outstanding,
// then workgroup barrier. SINGLE asm block + memory clobber so the compiler
// cannot schedule any LDS read between the wait and the barrier (s_barrier
// alone is NOT a memory fence in LLVM's model).
#define VM_BARRIER(N) asm volatile("s_waitcnt vmcnt(" #N ")\n\ts_barrier" ::: "memory")

static __device__ __forceinline__ ushort_t f2bf(float f) {
    union { float f; unsigned u; } a; a.f = f;
    const unsigned u = a.u;
    const unsigned r = u + 0x7FFFu + ((u >> 16) & 1u);
    return (ushort_t)(r >> 16);
}
static __device__ __forceinline__ float bf2f(ushort_t h) {
    union { unsigned u; float f; } a; a.u = ((unsigned)h) << 16; return a.f;
}
// interleaved pair store: dst[0,2,4,6] = a, dst[1,3,5,7] = b  (two b128 writes)
static __device__ __forceinline__ void st4p(float* dst, u16x4 a, u16x4 b) {
    *(f32x4*)(dst + 0) = f32x4{ bf2f(a[0]), bf2f(b[0]), bf2f(a[1]), bf2f(b[1]) };
    *(f32x4*)(dst + 4) = f32x4{ bf2f(a[2]), bf2f(b[2]), bf2f(a[3]), bf2f(b[3]) };
}
static __device__ __forceinline__ unsigned pk2(float lo, float hi) {
    return (unsigned)f2bf(lo) | ((unsigned)f2bf(hi) << 16);
}

// ---------------- Kernel 0: one-time prep --------------------------------
__launch_bounds__(256)
__global__ void prep(const float* __restrict__ x, const float* __restrict__ wsrc,
                     ushort_t* __restrict__ xT, ushort_t* __restrict__ wbf) {
    const int bid = blockIdx.x;
    const int t = threadIdx.x;
    if (bid < 512) {
        const int nt = bid & 15, kt = (bid >> 4) & 3, b = bid >> 6;
        const int n0 = nt * 64, k0 = kt * 64;
        __shared__ float Ts[64][65];     // +1 pad: column reads 2-way free
        const int kr = t >> 2, c4 = t & 3;
        const float* src = x + (size_t)b * (CIN * 1024) + (size_t)(k0 + kr) * 1024 + n0 + c4 * 16;
        const float4 v0 = *(const float4*)(src + 0);
        const float4 v1 = *(const float4*)(src + 4);
        const float4 v2 = *(const float4*)(src + 8);
        const float4 v3 = *(const float4*)(src + 12);
        float* d = &Ts[kr][c4 * 16];
        *(float4*)(d + 0) = v0; *(float4*)(d + 4) = v1;
        *(float4*)(d + 8) = v2; *(float4*)(d + 12) = v3;
        __syncthreads();
        const int nr = t >> 2, k4 = t & 3;
        unsigned pk[8];
        #pragma unroll
        for (int i = 0; i < 8; ++i)
            pk[i] = pk2(Ts[k4 * 16 + 2 * i][nr], Ts[k4 * 16 + 2 * i + 1][nr]);
        ushort_t* dst = xT + (size_t)b * (1024 * 256) + (size_t)(n0 + nr) * 256 + k0 + k4 * 16;
        *(uint4*)(dst + 0) = uint4{ pk[0], pk[1], pk[2], pk[3] };
        *(uint4*)(dst + 8) = uint4{ pk[4], pk[5], pk[6], pk[7] };
    } else {
        const int wid = bid - 512;       // 96 blocks x 2048 elems
        const size_t idx = (size_t)wid * 2048 + (size_t)t * 8;
        const float4 u0 = *(const float4*)(wsrc + idx);
        const float4 u1 = *(const float4*)(wsrc + idx + 4);
        uint4 o;
        o.x = pk2(u0.x, u0.y); o.y = pk2(u0.z, u0.w);
        o.z = pk2(u1.x, u1.y); o.w = pk2(u1.z, u1.w);
        *(uint4*)(wbf + idx) = o;
    }
}

// ---------------- Kernel 1: bf16 MFMA GEMM -> attn + rowAgg ------------------
// Split-K staged pipeline: LDS layout [khalf][row][128] so each half's
// global_load_lds destinations are lane-linear (m104 constraint). Issue both
// halves' loads, then fused {s_waitcnt vmcnt(4); s_barrier} -> compute K<128
// while the second half's loads stay in flight -> {vmcnt(0); s_barrier} ->
// K>=128. Halves the exposed staging drain vs __syncthreads' vmcnt(0).
__launch_bounds__(256)
__global__ void conv_gemm(const ushort_t* __restrict__ wbf, const ushort_t* __restrict__ xT,
                          const float* __restrict__ bias, ushort_t* __restrict__ attn,
                          float* __restrict__ rowAgg) {
    const int t = threadIdx.x;
    const int wv = t >> 6, lane = t & 63;
    const int q = lane >> 4, l15 = lane & 15;
    const int m0 = blockIdx.y * 64;
    const int mw = wv * 16;
    const int n_t = blockIdx.x * 64;
    const int b = n_t >> 10, nl0 = n_t & 1023;
    const int y0 = nl0 >> 5;

    __shared__ ushort_t Bs[16384];       // [khalf][row][128] bf16, 32768 B
    ushort_t (*Ct)[2][44] = (ushort_t (*)[2][44])(&Bs[0]);
    float (*red)[11]      = (float (*)[11])((char*)(&Bs[0]) + 64 * 2 * 44 * 2);

    // ---- stage B in two K-halves; per half, chunk c = row*16 + s7 is
    //      lane-linear in LDS; source swizzled s7^(row&7) (stays in-half).
    {
        const ushort_t* src = xT + (size_t)b * (1024 * 256) + (size_t)nl0 * 256;
        #pragma unroll
        for (int i = 0; i < 4; ++i) {               // half 0: k < 128
            const int c = i * 256 + t;              // 0..1023
            const int row = c >> 4, s7 = c & 15;
            const int ss = s7 ^ (row & 7);
            __builtin_amdgcn_global_load_lds((gas_ptr_t)(src + row * 256 + (ss << 3)),
                                             (las_ptr_t)&Bs[c * 8], 16, 0, 0);
        }
        #pragma unroll
        for (int i = 0; i < 4; ++i) {               // half 1: k >= 128
            const int c = i * 256 + t;
            const int row = c >> 4, s7 = c & 15;
            const int ss = s7 ^ (row & 7);
            __builtin_amdgcn_global_load_lds((gas_ptr_t)(src + row * 256 + ((16 + ss) << 3)),
                                             (las_ptr_t)&Bs[8192 + c * 8], 16, 0, 0);
        }
    }
    VM_BARRIER(4);      // own half-0 loads done + all waves arrived

    const ushort_t* aPf = wbf + (size_t)(m0 + mw + l15) * 256 + q * 8;
    const int e7 = l15 & 7;

    f32x4 acc[4] = {{0,0,0,0},{0,0,0,0},{0,0,0,0},{0,0,0,0}};
    #pragma unroll
    for (int k0 = 0; k0 < 128; k0 += 32) {            // K-half 0 (2nd half in flight)
        const s16x8 a = *(const s16x8*)(aPf + k0);
        const int ch = ((k0 >> 3) + q) ^ e7;          // 0..15 in-half, swizzled
        const ushort_t* bp = &Bs[l15 * 128 + ch * 8];
        const s16x8 b0 = *(const s16x8*)(bp +  0 * 128);
        const s16x8 b1 = *(const s16x8*)(bp + 16 * 128);
        const s16x8 b2 = *(const s16x8*)(bp + 32 * 128);
        const s16x8 b3 = *(const s16x8*)(bp + 48 * 128);
        acc[0] = __builtin_amdgcn_mfma_f32_16x16x32_bf16(a, b0, acc[0], 0, 0, 0);
        acc[1] = __builtin_amdgcn_mfma_f32_16x16x32_bf16(a, b1, acc[1], 0, 0, 0);
        acc[2] = __builtin_amdgcn_mfma_f32_16x16x32_bf16(a, b2, acc[2], 0, 0, 0);
        acc[3] = __builtin_amdgcn_mfma_f32_16x16x32_bf16(a, b3, acc[3], 0, 0, 0);
    }
    VM_BARRIER(0);      // all staging loads done + all waves arrived
    #pragma unroll
    for (int k0 = 128; k0 < 256; k0 += 32) {          // K-half 1
        const s16x8 a = *(const s16x8*)(aPf + k0);
        const int ch = (((k0 & 127) >> 3) + q) ^ e7;
        const ushort_t* bp = &Bs[8192 + l15 * 128 + ch * 8];
        const s16x8 b0 = *(const s16x8*)(bp +  0 * 128);
        const s16x8 b1 = *(const s16x8*)(bp + 16 * 128);
        const s16x8 b2 = *(const s16x8*)(bp + 32 * 128);
        const s16x8 b3 = *(const s16x8*)(bp + 48 * 128);
        acc[0] = __builtin_amdgcn_mfma_f32_16x16x32_bf16(a, b0, acc[0], 0, 0, 0);
        acc[1] = __builtin_amdgcn_mfma_f32_16x16x32_bf16(a, b1, acc[1], 0, 0, 0);
        acc[2] = __builtin_amdgcn_mfma_f32_16x16x32_bf16(a, b2, acc[2], 0, 0, 0);
        acc[3] = __builtin_amdgcn_mfma_f32_16x16x32_bf16(a, b3, acc[3], 0, 0, 0);
    }
    __syncthreads();   // Bs dead; Ct/red aliasing begins

    float bb[4];
    #pragma unroll
    for (int r = 0; r < 4; ++r) bb[r] = bias[m0 + mw + q * 4 + r];
    #pragma unroll
    for (int j = 0; j < 4; ++j) {
        const int yy = j >> 1, xx = (j & 1) * 16 + l15;
        #pragma unroll
        for (int r = 0; r < 4; ++r)
            Ct[mw + q * 4 + r][yy][2 + xx] = f2bf(acc[j][r] + bb[r]);
    }
    #pragma unroll
    for (int it = 0; it < 2; ++it) {
        const int id = it * 256 + t;
        const int m = id >> 3, yy = (id >> 2) & 1, pos = id & 3;
        const int us = (pos == 0) ? 0 : (32 + 2 * pos);
        *(unsigned*)&Ct[m][yy][us] = 0u;
    }
    __syncthreads();

    ushort_t* pb = attn + ((size_t)(b * COUT + m0)) * PLANE;
    #pragma unroll
    for (int it = 0; it < 5; ++it) {
        const int id = it * 256 + t;
        const int m = id / 20, rem = id % 20, yy = rem / 10, s = rem % 10;
        const ull_t v = *(const ull_t*)&Ct[m][yy][s * 4];
        *(ull_t*)(pb + (size_t)m * PLANE + (y0 + yy + 2) * PW + s * 4) = v;
    }
    if (y0 == 0 || y0 == 30) {
        const int rowA = (y0 == 0) ? 0 : 34;
        #pragma unroll
        for (int it = 0; it < 5; ++it) {
            const int id = it * 256 + t;
            const int m = id / 20, rem = id % 20, yy = rem / 10, s = rem % 10;
            *(ull_t*)(pb + (size_t)m * PLANE + (rowA + yy) * PW + s * 4) = 0ull;
        }
    }

    if (t < 128) {
        const int gi = t >> 6, yy = (t >> 5) & 1, c = t & 31;
        const int m = gi * 32 + c;
        float lin = 0.f, sq = 0.f, e0 = 0.f, e1 = 0.f, e30 = 0.f, e31 = 0.f;
        #pragma unroll
        for (int u = 0; u < 9; ++u) {
            const ull_t vv = *(const ull_t*)&Ct[m][yy][u * 4];
            const unsigned lo = (unsigned)vv, hi = (unsigned)(vv >> 32);
            union { unsigned u; float f; } f0, f1, f2, f3;
            f0.u = lo << 16; f1.u = lo & 0xffff0000u;
            f2.u = hi << 16; f3.u = hi & 0xffff0000u;
            lin += (f0.f + f1.f) + (f2.f + f3.f);
            sq  += (f0.f * f0.f + f1.f * f1.f) + (f2.f * f2.f + f3.f * f3.f);
            if (u == 0) { e0 = f2.f; e1 = f3.f; }
            if (u == 8) { e30 = f0.f; e31 = f1.f; }
        }
        red[t][0] = lin; red[t][1] = sq;
        red[t][2] = e0;  red[t][3] = e0 * e0;
        red[t][4] = e1;  red[t][5] = e1 * e1;
        red[t][6] = e30; red[t][7] = e30 * e30;
        red[t][8] = e31; red[t][9] = e31 * e31;
    }
    __syncthreads();
    if (t < 40) {
        const int s = t % 10, gy = t / 10;
        const int gi = gy >> 1, yy = gy & 1;
        float sum = 0.f;
        #pragma unroll
        for (int c = 0; c < 32; ++c) sum += red[gi * 64 + yy * 32 + c][s];
        const int g = blockIdx.y * 2 + gi;
        rowAgg[(((size_t)b * G_ + g) * 32 + (y0 + yy)) * 10 + s] = sum;
    }
}

// ---------------- Kernel 2: local attention — 2-wave blocks, 2-row slabs.
// R8 structure (interleaved K/Q pairs, b64 tap reads, paired PV). Fence trims:
// last-iteration fences removed (QK's is covered by the following
// __syncthreads; PV's orders nothing) and the pre-PV fence removed (all prior
// LDS writes are covered by the exchange __syncthreads). -----------------------
__launch_bounds__(128)
__global__ void local_attn(const ushort_t* __restrict__ attn,
                           const float* __restrict__ rowAgg,
                           const float* __restrict__ gn_w, const float* __restrict__ gn_b,
                           float* __restrict__ out) {
    const int wid = blockIdx.x;          // 1024 = b(8) x n(8) x slab(16)
    const int b = wid >> 7;
    const int n = (wid >> 4) & 7;
    const int i0 = (wid & 15) * 2;       // first image row of the 2-row slab
    const int t = threadIdx.x;           // 128
    const int h = t >> 6;                // wave index = channel half
    const int lane = t & 63;
    const int r = lane >> 5;             // row within slab
    const int j = lane & 31;             // pixel column

    __shared__ float PB[2][2][480];      // [half][buf][240 taps x pair]
    __shared__ float ex[128][27];        // sal exchange, stride-27 conflict-free
    __shared__ float rpL[96][5], rp2L[96][5];
    __shared__ float s_m[75], s_r[75];
    __shared__ float s_rq[25], s_mq[25], s_rk[25], s_ck[25], s_rv[25], s_cv[25];
    __shared__ float s_gw[96], s_gb[96];

    // ---- staging bases + early issue of plane 0..2 loads (cover: gnfin) ----
    const ushort_t* regB = attn + (size_t)(b * COUT + n * 96) * PLANE + i0 * PW;
    const bool stg = (lane < 60);
    const int eo = lane * 4;
    const int b2 = 2 * (r * PW + j);     // word offset of this lane's window base
    const ushort_t* baseK = regB + (size_t)(h * 16) * PLANE;
    const ushort_t* baseQ = regB + (size_t)(32 + h * 16) * PLANE;
    const ushort_t* baseV = regB + (size_t)(64 + h * 16) * PLANE;

    u16x4 c0K{0,0,0,0}, c0Q{0,0,0,0};
    u16x4 nK{0,0,0,0}, nQ{0,0,0,0}, fK{0,0,0,0}, fQ{0,0,0,0};
    if (stg) {
        c0K = *(const u16x4*)(baseK + eo);
        c0Q = *(const u16x4*)(baseQ + eo);
        nK = *(const u16x4*)(baseK + (size_t)PLANE + eo);
        nQ = *(const u16x4*)(baseQ + (size_t)PLANE + eo);
        fK = *(const u16x4*)(baseK + 2 * (size_t)PLANE + eo);
        fQ = *(const u16x4*)(baseQ + 2 * (size_t)PLANE + eo);
    }

    if (t < 96) { s_gw[t] = gn_w[n * 96 + t]; s_gb[t] = gn_b[n * 96 + t]; }

    // ---- fused gnfin, phase 1: per-(group,row) window column sums ----------
    const float* rab = rowAgg + (size_t)((b * G_ + n * 3) * 32) * 10;
    if (t < 96) {
        const float* a = rab + (size_t)t * 10;
        const float S = a[0], Sq = a[1];
        const float e0 = a[2], q0 = a[3], e1 = a[4], q1v = a[5];
        const float e30 = a[6], q30 = a[7], e31 = a[8], q31 = a[9];
        rpL[t][0] = S - e30 - e31; rpL[t][1] = S - e31; rpL[t][2] = S;
        rpL[t][3] = S - e0;        rpL[t][4] = S - e0 - e1;
        rp2L[t][0] = Sq - q30 - q31; rp2L[t][1] = Sq - q31; rp2L[t][2] = Sq;
        rp2L[t][3] = Sq - q0;        rp2L[t][4] = Sq - q0 - q1v;
    }
    __syncthreads();

    // ---- fused gnfin, phase 2: 75 (group,window) mean/rstd entries ---------
    if (t < 75) {
        const int gi = t / 25, p = t % 25;
        const int kw = p % 5, kh = p / 5;
        const int rb = gi * 32;
        float cs = 0.f, cs2 = 0.f;
        #pragma unroll
        for (int yy = 0; yy < 32; ++yy) { cs += rpL[rb + yy][kw]; cs2 += rp2L[rb + yy][kw]; }
        if (kh == 0)      { cs -= rpL[rb + 30][kw] + rpL[rb + 31][kw]; cs2 -= rp2L[rb + 30][kw] + rp2L[rb + 31][kw]; }
        else if (kh == 1) { cs -= rpL[rb + 31][kw];                    cs2 -= rp2L[rb + 31][kw]; }
        else if (kh == 3) { cs -= rpL[rb + 0][kw];                     cs2 -= rp2L[rb + 0][kw]; }
        else if (kh == 4) { cs -= rpL[rb + 0][kw] + rpL[rb + 1][kw];   cs2 -= rp2L[rb + 0][kw] + rp2L[rb + 1][kw]; }
        const float inv_n = 1.f / 32768.f;
        const float mean = cs * inv_n;
        const float var  = cs2 * inv_n - mean * mean;
        s_m[t] = mean;
        s_r[t] = rsqrtf(var + EPS_);
    }
    __syncthreads();

    if (t < 25) {
        const float mK = s_m[t],      rK = s_r[t];
        const float mQ = s_m[25 + t], rQ = s_r[25 + t];
        const float mV = s_m[50 + t], rV = s_r[50 + t];
        s_rk[t] = rK; s_ck[t] = mK * rK;
        s_rq[t] = rQ; s_mq[t] = mQ * rQ;
        s_rv[t] = rV; s_cv[t] = mV * rV;
    }
    __syncthreads();

    float rq[25]; float cQ = 0.f;
    #pragma unroll
    for (int p = 0; p < 25; ++p) { rq[p] = s_rq[p]; cQ += s_mq[p]; }

    if (stg) st4p(&PB[h][0][2 * eo], c0K, c0Q);
    LDS_FENCE();

    float sal[25];
    #pragma unroll
    for (int p = 0; p < 25; ++p) sal[p] = 0.f;
    float sumQ2 = 0.f, sumQB = 0.f;

    #pragma unroll 2
    for (int cc = 0; cc < 16; ++cc) {
        const int buf = cc & 1;
        if (stg && cc < 15) {
            st4p(&PB[h][buf ^ 1][2 * eo], nK, nQ);    // plane cc+1 (K,Q interleaved)
            nK = fK; nQ = fQ;
            if (cc < 13) {                            // K/Q plane cc+3
                fK = *(const u16x4*)(baseK + (size_t)(cc + 3) * PLANE + eo);
                fQ = *(const u16x4*)(baseQ + (size_t)(cc + 3) * PLANE + eo);
            } else if (cc == 13) {                    // tail: V0,V1
                fK = *(const u16x4*)(baseV + eo);
                fQ = *(const u16x4*)(baseV + (size_t)PLANE + eo);
            } else {                                  // cc == 14: V2,V3
                fK = *(const u16x4*)(baseV + 2 * (size_t)PLANE + eo);
                fQ = *(const u16x4*)(baseV + 3 * (size_t)PLANE + eo);
            }
        }
        const int ch = h * 16 + cc;
        const float* pb = &PB[h][buf][0];
        float kv[25];
        float qa0 = 0.f, qa1 = 0.f, qa2 = 0.f, qa3 = 0.f, qa4 = 0.f;
        #pragma unroll
        for (int kw = 0; kw < 5; ++kw) {
            const float2 t0 = *(const float2*)&pb[b2 + 2 * (0 * PW + kw)];
            const float2 t1 = *(const float2*)&pb[b2 + 2 * (1 * PW + kw)];
            const float2 t2 = *(const float2*)&pb[b2 + 2 * (2 * PW + kw)];
            const float2 t3 = *(const float2*)&pb[b2 + 2 * (3 * PW + kw)];
            const float2 t4 = *(const float2*)&pb[b2 + 2 * (4 * PW + kw)];
            kv[0 * 5 + kw] = t0.x; qa0 += rq[0 * 5 + kw] * t0.y;
            kv[1 * 5 + kw] = t1.x; qa1 += rq[1 * 5 + kw] * t1.y;
            kv[2 * 5 + kw] = t2.x; qa2 += rq[2 * 5 + kw] * t2.y;
            kv[3 * 5 + kw] = t3.x; qa3 += rq[3 * 5 + kw] * t3.y;
            kv[4 * 5 + kw] = t4.x; qa4 += rq[4 * 5 + kw] * t4.y;
        }
        const float qa = (qa0 + qa1) + (qa2 + qa3) + qa4;
        const float qk  = s_gw[32 + ch] * ((qa - cQ) * 0.04f) + s_gb[32 + ch];
        const float qk2 = qk * s_gw[ch];
        sumQ2 += qk2; sumQB += qk * s_gb[ch];
        #pragma unroll
        for (int p = 0; p < 25; ++p) sal[p] += qk2 * kv[p];
        if (cc < 15) LDS_FENCE();       // last iter: covered by __syncthreads
    }
    // exit: nK,nQ = V0,V1 ; fK,fQ = V2,V3

    // cross-wave exchange: write partials + stage V pair0, barrier
    #pragma unroll
    for (int p = 0; p < 25; ++p) ex[t][p] = sal[p];
    ex[t][25] = sumQ2; ex[t][26] = sumQB;
    if (stg) st4p(&PB[h][0][2 * eo], nK, nQ);   // pair0 = (V0,V1) -> buf0
    __syncthreads();
    const int par = t ^ 64;
    #pragma unroll
    for (int p = 0; p < 25; ++p) sal[p] += ex[par][p];
    sumQ2 += ex[par][25]; sumQB += ex[par][26];

    u16x4 vA0 = fK, vA1 = fQ;                    // pair1 = (V2,V3)
    u16x4 vB0{0,0,0,0}, vB1{0,0,0,0};
    if (stg) {                                   // pair2 = (V4,V5), post-barrier
        vB0 = *(const u16x4*)(baseV + 4 * (size_t)PLANE + eo);
        vB1 = *(const u16x4*)(baseV + 5 * (size_t)PLANE + eo);
    }

    #pragma unroll
    for (int p = 0; p < 25; ++p) sal[p] = s_rk[p] * sal[p] - s_ck[p] * sumQ2 + sumQB;

    const float scale = 0.17677669529663687f;  // 1/sqrt(32)
    float mmax = -3.4e38f;
    #pragma unroll
    for (int p = 0; p < 25; ++p) { sal[p] *= scale; mmax = fmaxf(mmax, sal[p]); }
    float ssum = 0.f;
    #pragma unroll
    for (int p = 0; p < 25; ++p) { sal[p] = __expf(sal[p] - mmax); ssum += sal[p]; }
    const float rs = 1.f / ssum;
    float cV2 = 0.f;
    #pragma unroll
    for (int p = 0; p < 25; ++p) {
        const float m = sal[p] * rs;
        sal[p] = m * s_rv[p];        // reuse sal as V-tap weights
        cV2 += m * s_cv[p];
    }
    // (no fence needed: PB buf0 write happened before __syncthreads above)

    // PV: 8 iterations, TWO V planes each (pair vp from buf vp&1)
    #pragma unroll 2
    for (int vp = 0; vp < 8; ++vp) {
        const int buf = vp & 1;
        if (stg && vp < 7) {
            st4p(&PB[h][buf ^ 1][2 * eo], vA0, vA1);   // pair vp+1
            vA0 = vB0; vA1 = vB1;
            if (vp < 5) {                              // pair vp+3 = planes 2vp+6, 2vp+7
                vB0 = *(const u16x4*)(baseV + (size_t)(2 * vp + 6) * PLANE + eo);
                vB1 = *(const u16x4*)(baseV + (size_t)(2 * vp + 7) * PLANE + eo);
            }
        }
        const int v0 = h * 16 + 2 * vp;
        const float* pb = &PB[h][buf][0];
        float l0 = 0.f, l1 = 0.f, l2 = 0.f, l3 = 0.f, l4 = 0.f;
        float g0 = 0.f, g1 = 0.f, g2 = 0.f, g3 = 0.f, g4 = 0.f;
        #pragma unroll
        for (int kw = 0; kw < 5; ++kw) {
            const float2 t0 = *(const float2*)&pb[b2 + 2 * (0 * PW + kw)];
            const float2 t1 = *(const float2*)&pb[b2 + 2 * (1 * PW + kw)];
            const float2 t2 = *(const float2*)&pb[b2 + 2 * (2 * PW + kw)];
            const float2 t3 = *(const float2*)&pb[b2 + 2 * (3 * PW + kw)];
            const float2 t4 = *(const float2*)&pb[b2 + 2 * (4 * PW + kw)];
            l0 += sal[0 * 5 + kw] * t0.x; g0 += sal[0 * 5 + kw] * t0.y;
            l1 += sal[1 * 5 + kw] * t1.x; g1 += sal[1 * 5 + kw] * t1.y;
            l2 += sal[2 * 5 + kw] * t2.x; g2 += sal[2 * 5 + kw] * t2.y;
            l3 += sal[3 * 5 + kw] * t3.x; g3 += sal[3 * 5 + kw] * t3.y;
            l4 += sal[4 * 5 + kw] * t4.x; g4 += sal[4 * 5 + kw] * t4.y;
        }
        const float aL = (l0 + l1) + (l2 + l3) + l4;
        const float aH = (g0 + g1) + (g2 + g3) + g4;
        const size_t ob = ((size_t)(b * 256 + n * 32 + v0) * 32 + (i0 + r)) * 32 + j;
        out[ob]        = s_gw[64 + v0] * aL + (s_gb[64 + v0] - s_gw[64 + v0] * cV2);
        out[ob + 1024] = s_gw[65 + v0] * aH + (s_gb[65 + v0] - s_gw[65 + v0] * cV2);
        if (vp < 7) LDS_FENCE();        // last iter: nothing left to order
    }
}

extern "C" void kernel_launch(void* const* d_in, const int* in_sizes, int n_in,
                              void* d_out, int out_size, void* d_ws, size_t ws_size,
                              hipStream_t stream) {
    const float* x      = (const float*)d_in[0];
    const float* conv_w = (const float*)d_in[1];
    const float* conv_b = (const float*)d_in[2];
    const float* gn_w   = (const float*)d_in[3];
    const float* gn_b   = (const float*)d_in[4];
    float* out = (float*)d_out;

    // ws: attn bf16 padded | rowAgg f32 | xT bf16 | wbf bf16
    ushort_t* attn    = (ushort_t*)d_ws;                    // 8,847,360 ushorts
    float*    rowAgg  = (float*)(attn + 8847360);           // 61,440 floats
    ushort_t* xT      = (ushort_t*)(rowAgg + 61440);        // 2,097,152 ushorts
    ushort_t* wbf     = xT + 2097152;                       // 196,608 ushorts

    prep<<<608, 256, 0, stream>>>(x, conv_w, xT, wbf);
    conv_gemm<<<dim3(128, 12), 256, 0, stream>>>(wbf, xT, conv_b, attn, rowAgg);
    local_attn<<<1024, 128, 0, stream>>>(attn, rowAgg, gn_w, gn_b, out);
}

// Round 11
// 106.401 us; speedup vs baseline: 1.9042x; 1.0056x over previous
//
#include <hip/hip_runtime.h>
#include <hip/hip_bf16.h>

#define B_    8
#define CIN   256
#define COUT  768
#define G_    24
#define PW    40         // padded row width (16B-aligned rows)
#define PLANE 1440       // 40*36
#define EPS_  1e-5f

typedef float f32x4 __attribute__((ext_vector_type(4)));
typedef short s16x8 __attribute__((ext_vector_type(8)));
typedef unsigned short ushort_t;
typedef unsigned short u16x4 __attribute__((ext_vector_type(4)));
typedef unsigned long long ull_t;

typedef const __attribute__((address_space(1))) void* gas_ptr_t;
typedef __attribute__((address_space(3))) void* las_ptr_t;

// Counted-vmcnt barrier: wait until <=N of this wave's vmem ops outstanding,
// then workgroup barrier. SINGLE asm block + memory clobber so the compiler
// cannot schedule any LDS read between the wait and the barrier (s_barrier
// alone is NOT a memory fence in LLVM's model).
#define VM_BARRIER(N) asm volatile("s_waitcnt vmcnt(" #N ")\n\ts_barrier" ::: "memory")

static __device__ __forceinline__ ushort_t f2bf(float f) {
    union { float f; unsigned u; } a; a.f = f;
    const unsigned u = a.u;
    const unsigned r = u + 0x7FFFu + ((u >> 16) & 1u);
    return (ushort_t)(r >> 16);
}
static __device__ __forceinline__ float bf2f(ushort_t h) {
    union { unsigned u; float f; } a; a.u = ((unsigned)h) << 16; return a.f;
}
// interleaved pair store: dst[0,2,4,6] = a, dst[1,3,5,7] = b  (two b128 writes)
static __device__ __forceinline__ void st4p(float* dst, u16x4 a, u16x4 b) {
    *(f32x4*)(dst + 0) = f32x4{ bf2f(a[0]), bf2f(b[0]), bf2f(a[1]), bf2f(b[1]) };
    *(f32x4*)(dst + 4) = f32x4{ bf2f(a[2]), bf2f(b[2]), bf2f(a[3]), bf2f(b[3]) };
}
static __device__ __forceinline__ unsigned pk2(float lo, float hi) {
    return (unsigned)f2bf(lo) | ((unsigned)f2bf(hi) << 16);
}

// ---------------- Kernel 0: one-time prep --------------------------------
__launch_bounds__(256)
__global__ void prep(const float* __restrict__ x, const float* __restrict__ wsrc,
                     ushort_t* __restrict__ xT, ushort_t* __restrict__ wbf) {
    const int bid = blockIdx.x;
    const int t = threadIdx.x;
    if (bid < 512) {
        const int nt = bid & 15, kt = (bid >> 4) & 3, b = bid >> 6;
        const int n0 = nt * 64, k0 = kt * 64;
        __shared__ float Ts[64][65];     // +1 pad: column reads 2-way free
        const int kr = t >> 2, c4 = t & 3;
        const float* src = x + (size_t)b * (CIN * 1024) + (size_t)(k0 + kr) * 1024 + n0 + c4 * 16;
        const float4 v0 = *(const float4*)(src + 0);
        const float4 v1 = *(const float4*)(src + 4);
        const float4 v2 = *(const float4*)(src + 8);
        const float4 v3 = *(const float4*)(src + 12);
        float* d = &Ts[kr][c4 * 16];
        *(float4*)(d + 0) = v0; *(float4*)(d + 4) = v1;
        *(float4*)(d + 8) = v2; *(float4*)(d + 12) = v3;
        __syncthreads();
        const int nr = t >> 2, k4 = t & 3;
        unsigned pk[8];
        #pragma unroll
        for (int i = 0; i < 8; ++i)
            pk[i] = pk2(Ts[k4 * 16 + 2 * i][nr], Ts[k4 * 16 + 2 * i + 1][nr]);
        ushort_t* dst = xT + (size_t)b * (1024 * 256) + (size_t)(n0 + nr) * 256 + k0 + k4 * 16;
        *(uint4*)(dst + 0) = uint4{ pk[0], pk[1], pk[2], pk[3] };
        *(uint4*)(dst + 8) = uint4{ pk[4], pk[5], pk[6], pk[7] };
    } else {
        const int wid = bid - 512;       // 96 blocks x 2048 elems
        const size_t idx = (size_t)wid * 2048 + (size_t)t * 8;
        const float4 u0 = *(const float4*)(wsrc + idx);
        const float4 u1 = *(const float4*)(wsrc + idx + 4);
        uint4 o;
        o.x = pk2(u0.x, u0.y); o.y = pk2(u0.z, u0.w);
        o.z = pk2(u1.x, u1.y); o.w = pk2(u1.z, u1.w);
        *(uint4*)(wbf + idx) = o;
    }
}

// ---------------- Kernel 1: bf16 MFMA GEMM -> attn + rowAgg ------------------
// (unchanged from R10: split-K global_load_lds stage with counted-vmcnt fused
// barriers; flat source-swizzled LDS)
__launch_bounds__(256)
__global__ void conv_gemm(const ushort_t* __restrict__ wbf, const ushort_t* __restrict__ xT,
                          const float* __restrict__ bias, ushort_t* __restrict__ attn,
                          float* __restrict__ rowAgg) {
    const int t = threadIdx.x;
    const int wv = t >> 6, lane = t & 63;
    const int q = lane >> 4, l15 = lane & 15;
    const int m0 = blockIdx.y * 64;
    const int mw = wv * 16;
    const int n_t = blockIdx.x * 64;
    const int b = n_t >> 10, nl0 = n_t & 1023;
    const int y0 = nl0 >> 5;

    __shared__ ushort_t Bs[16384];       // [khalf][row][128] bf16, 32768 B
    ushort_t (*Ct)[2][44] = (ushort_t (*)[2][44])(&Bs[0]);
    float (*red)[11]      = (float (*)[11])((char*)(&Bs[0]) + 64 * 2 * 44 * 2);

    // ---- stage B in two K-halves; per half, chunk c = row*16 + s7 is
    //      lane-linear in LDS; source swizzled s7^(row&7) (stays in-half).
    {
        const ushort_t* src = xT + (size_t)b * (1024 * 256) + (size_t)nl0 * 256;
        #pragma unroll
        for (int i = 0; i < 4; ++i) {               // half 0: k < 128
            const int c = i * 256 + t;              // 0..1023
            const int row = c >> 4, s7 = c & 15;
            const int ss = s7 ^ (row & 7);
            __builtin_amdgcn_global_load_lds((gas_ptr_t)(src + row * 256 + (ss << 3)),
                                             (las_ptr_t)&Bs[c * 8], 16, 0, 0);
        }
        #pragma unroll
        for (int i = 0; i < 4; ++i) {               // half 1: k >= 128
            const int c = i * 256 + t;
            const int row = c >> 4, s7 = c & 15;
            const int ss = s7 ^ (row & 7);
            __builtin_amdgcn_global_load_lds((gas_ptr_t)(src + row * 256 + ((16 + ss) << 3)),
                                             (las_ptr_t)&Bs[8192 + c * 8], 16, 0, 0);
        }
    }
    VM_BARRIER(4);      // own half-0 loads done + all waves arrived

    const ushort_t* aPf = wbf + (size_t)(m0 + mw + l15) * 256 + q * 8;
    const int e7 = l15 & 7;

    f32x4 acc[4] = {{0,0,0,0},{0,0,0,0},{0,0,0,0},{0,0,0,0}};
    #pragma unroll
    for (int k0 = 0; k0 < 128; k0 += 32) {            // K-half 0 (2nd half in flight)
        const s16x8 a = *(const s16x8*)(aPf + k0);
        const int ch = ((k0 >> 3) + q) ^ e7;          // 0..15 in-half, swizzled
        const ushort_t* bp = &Bs[l15 * 128 + ch * 8];
        const s16x8 b0 = *(const s16x8*)(bp +  0 * 128);
        const s16x8 b1 = *(const s16x8*)(bp + 16 * 128);
        const s16x8 b2 = *(const s16x8*)(bp + 32 * 128);
        const s16x8 b3 = *(const s16x8*)(bp + 48 * 128);
        acc[0] = __builtin_amdgcn_mfma_f32_16x16x32_bf16(a, b0, acc[0], 0, 0, 0);
        acc[1] = __builtin_amdgcn_mfma_f32_16x16x32_bf16(a, b1, acc[1], 0, 0, 0);
        acc[2] = __builtin_amdgcn_mfma_f32_16x16x32_bf16(a, b2, acc[2], 0, 0, 0);
        acc[3] = __builtin_amdgcn_mfma_f32_16x16x32_bf16(a, b3, acc[3], 0, 0, 0);
    }
    VM_BARRIER(0);      // all staging loads done + all waves arrived
    #pragma unroll
    for (int k0 = 128; k0 < 256; k0 += 32) {          // K-half 1
        const s16x8 a = *(const s16x8*)(aPf + k0);
        const int ch = (((k0 & 127) >> 3) + q) ^ e7;
        const ushort_t* bp = &Bs[8192 + l15 * 128 + ch * 8];
        const s16x8 b0 = *(const s16x8*)(bp +  0 * 128);
        const s16x8 b1 = *(const s16x8*)(bp + 16 * 128);
        const s16x8 b2 = *(const s16x8*)(bp + 32 * 128);
        const s16x8 b3 = *(const s16x8*)(bp + 48 * 128);
        acc[0] = __builtin_amdgcn_mfma_f32_16x16x32_bf16(a, b0, acc[0], 0, 0, 0);
        acc[1] = __builtin_amdgcn_mfma_f32_16x16x32_bf16(a, b1, acc[1], 0, 0, 0);
        acc[2] = __builtin_amdgcn_mfma_f32_16x16x32_bf16(a, b2, acc[2], 0, 0, 0);
        acc[3] = __builtin_amdgcn_mfma_f32_16x16x32_bf16(a, b3, acc[3], 0, 0, 0);
    }
    __syncthreads();   // Bs dead; Ct/red aliasing begins

    float bb[4];
    #pragma unroll
    for (int r = 0; r < 4; ++r) bb[r] = bias[m0 + mw + q * 4 + r];
    #pragma unroll
    for (int j = 0; j < 4; ++j) {
        const int yy = j >> 1, xx = (j & 1) * 16 + l15;
        #pragma unroll
        for (int r = 0; r < 4; ++r)
            Ct[mw + q * 4 + r][yy][2 + xx] = f2bf(acc[j][r] + bb[r]);
    }
    #pragma unroll
    for (int it = 0; it < 2; ++it) {
        const int id = it * 256 + t;
        const int m = id >> 3, yy = (id >> 2) & 1, pos = id & 3;
        const int us = (pos == 0) ? 0 : (32 + 2 * pos);
        *(unsigned*)&Ct[m][yy][us] = 0u;
    }
    __syncthreads();

    ushort_t* pb = attn + ((size_t)(b * COUT + m0)) * PLANE;
    #pragma unroll
    for (int it = 0; it < 5; ++it) {
        const int id = it * 256 + t;
        const int m = id / 20, rem = id % 20, yy = rem / 10, s = rem % 10;
        const ull_t v = *(const ull_t*)&Ct[m][yy][s * 4];
        *(ull_t*)(pb + (size_t)m * PLANE + (y0 + yy + 2) * PW + s * 4) = v;
    }
    if (y0 == 0 || y0 == 30) {
        const int rowA = (y0 == 0) ? 0 : 34;
        #pragma unroll
        for (int it = 0; it < 5; ++it) {
            const int id = it * 256 + t;
            const int m = id / 20, rem = id % 20, yy = rem / 10, s = rem % 10;
            *(ull_t*)(pb + (size_t)m * PLANE + (rowA + yy) * PW + s * 4) = 0ull;
        }
    }

    if (t < 128) {
        const int gi = t >> 6, yy = (t >> 5) & 1, c = t & 31;
        const int m = gi * 32 + c;
        float lin = 0.f, sq = 0.f, e0 = 0.f, e1 = 0.f, e30 = 0.f, e31 = 0.f;
        #pragma unroll
        for (int u = 0; u < 9; ++u) {
            const ull_t vv = *(const ull_t*)&Ct[m][yy][u * 4];
            const unsigned lo = (unsigned)vv, hi = (unsigned)(vv >> 32);
            union { unsigned u; float f; } f0, f1, f2, f3;
            f0.u = lo << 16; f1.u = lo & 0xffff0000u;
            f2.u = hi << 16; f3.u = hi & 0xffff0000u;
            lin += (f0.f + f1.f) + (f2.f + f3.f);
            sq  += (f0.f * f0.f + f1.f * f1.f) + (f2.f * f2.f + f3.f * f3.f);
            if (u == 0) { e0 = f2.f; e1 = f3.f; }
            if (u == 8) { e30 = f0.f; e31 = f1.f; }
        }
        red[t][0] = lin; red[t][1] = sq;
        red[t][2] = e0;  red[t][3] = e0 * e0;
        red[t][4] = e1;  red[t][5] = e1 * e1;
        red[t][6] = e30; red[t][7] = e30 * e30;
        red[t][8] = e31; red[t][9] = e31 * e31;
    }
    __syncthreads();
    if (t < 40) {
        const int s = t % 10, gy = t / 10;
        const int gi = gy >> 1, yy = gy & 1;
        float sum = 0.f;
        #pragma unroll
        for (int c = 0; c < 32; ++c) sum += red[gi * 64 + yy * 32 + c][s];
        const int g = blockIdx.y * 2 + gi;
        rowAgg[(((size_t)b * G_ + g) * 32 + (y0 + yy)) * 10 + s] = sum;
    }
}

// ---------------- Kernel 2: local attention — 2-wave blocks, 2-row slabs.
// FENCE-FREE staging loops: the double-buffered PB is wave-private, and LDS
// ops from one wave are processed in order (single in-order DS pipe), so
// write(buf^1, iter cc) -> read(buf^1, iter cc+1) is ordered by program order
// alone; the compiler inserts counted lgkmcnt for read->use deps. The old
// per-iteration lgkmcnt(0) fences drained ~10 outstanding ds_writes every
// iteration for nothing. Cross-wave exchange keeps its __syncthreads. -------
__launch_bounds__(128)
__global__ void local_attn(const ushort_t* __restrict__ attn,
                           const float* __restrict__ rowAgg,
                           const float* __restrict__ gn_w, const float* __restrict__ gn_b,
                           float* __restrict__ out) {
    const int wid = blockIdx.x;          // 1024 = b(8) x n(8) x slab(16)
    const int b = wid >> 7;
    const int n = (wid >> 4) & 7;
    const int i0 = (wid & 15) * 2;       // first image row of the 2-row slab
    const int t = threadIdx.x;           // 128
    const int h = t >> 6;                // wave index = channel half
    const int lane = t & 63;
    const int r = lane >> 5;             // row within slab
    const int j = lane & 31;             // pixel column

    __shared__ float PB[2][2][480];      // [half][buf][240 taps x pair]
    __shared__ float ex[128][27];        // sal exchange, stride-27 conflict-free
    __shared__ float rpL[96][5], rp2L[96][5];
    __shared__ float s_m[75], s_r[75];
    __shared__ float s_rq[25], s_mq[25], s_rk[25], s_ck[25], s_rv[25], s_cv[25];
    __shared__ float s_gw[96], s_gb[96];

    // ---- staging bases + early issue of plane 0..2 loads (cover: gnfin) ----
    const ushort_t* regB = attn + (size_t)(b * COUT + n * 96) * PLANE + i0 * PW;
    const bool stg = (lane < 60);
    const int eo = lane * 4;
    const int b2 = 2 * (r * PW + j);     // word offset of this lane's window base
    const ushort_t* baseK = regB + (size_t)(h * 16) * PLANE;
    const ushort_t* baseQ = regB + (size_t)(32 + h * 16) * PLANE;
    const ushort_t* baseV = regB + (size_t)(64 + h * 16) * PLANE;

    u16x4 c0K{0,0,0,0}, c0Q{0,0,0,0};
    u16x4 nK{0,0,0,0}, nQ{0,0,0,0}, fK{0,0,0,0}, fQ{0,0,0,0};
    if (stg) {
        c0K = *(const u16x4*)(baseK + eo);
        c0Q = *(const u16x4*)(baseQ + eo);
        nK = *(const u16x4*)(baseK + (size_t)PLANE + eo);
        nQ = *(const u16x4*)(baseQ + (size_t)PLANE + eo);
        fK = *(const u16x4*)(baseK + 2 * (size_t)PLANE + eo);
        fQ = *(const u16x4*)(baseQ + 2 * (size_t)PLANE + eo);
    }

    if (t < 96) { s_gw[t] = gn_w[n * 96 + t]; s_gb[t] = gn_b[n * 96 + t]; }

    // ---- fused gnfin, phase 1: per-(group,row) window column sums ----------
    const float* rab = rowAgg + (size_t)((b * G_ + n * 3) * 32) * 10;
    if (t < 96) {
        const float* a = rab + (size_t)t * 10;
        const float S = a[0], Sq = a[1];
        const float e0 = a[2], q0 = a[3], e1 = a[4], q1v = a[5];
        const float e30 = a[6], q30 = a[7], e31 = a[8], q31 = a[9];
        rpL[t][0] = S - e30 - e31; rpL[t][1] = S - e31; rpL[t][2] = S;
        rpL[t][3] = S - e0;        rpL[t][4] = S - e0 - e1;
        rp2L[t][0] = Sq - q30 - q31; rp2L[t][1] = Sq - q31; rp2L[t][2] = Sq;
        rp2L[t][3] = Sq - q0;        rp2L[t][4] = Sq - q0 - q1v;
    }
    __syncthreads();

    // ---- fused gnfin, phase 2: 75 (group,window) mean/rstd entries ---------
    if (t < 75) {
        const int gi = t / 25, p = t % 25;
        const int kw = p % 5, kh = p / 5;
        const int rb = gi * 32;
        float cs = 0.f, cs2 = 0.f;
        #pragma unroll
        for (int yy = 0; yy < 32; ++yy) { cs += rpL[rb + yy][kw]; cs2 += rp2L[rb + yy][kw]; }
        if (kh == 0)      { cs -= rpL[rb + 30][kw] + rpL[rb + 31][kw]; cs2 -= rp2L[rb + 30][kw] + rp2L[rb + 31][kw]; }
        else if (kh == 1) { cs -= rpL[rb + 31][kw];                    cs2 -= rp2L[rb + 31][kw]; }
        else if (kh == 3) { cs -= rpL[rb + 0][kw];                     cs2 -= rp2L[rb + 0][kw]; }
        else if (kh == 4) { cs -= rpL[rb + 0][kw] + rpL[rb + 1][kw];   cs2 -= rp2L[rb + 0][kw] + rp2L[rb + 1][kw]; }
        const float inv_n = 1.f / 32768.f;
        const float mean = cs * inv_n;
        const float var  = cs2 * inv_n - mean * mean;
        s_m[t] = mean;
        s_r[t] = rsqrtf(var + EPS_);
    }
    __syncthreads();

    if (t < 25) {
        const float mK = s_m[t],      rK = s_r[t];
        const float mQ = s_m[25 + t], rQ = s_r[25 + t];
        const float mV = s_m[50 + t], rV = s_r[50 + t];
        s_rk[t] = rK; s_ck[t] = mK * rK;
        s_rq[t] = rQ; s_mq[t] = mQ * rQ;
        s_rv[t] = rV; s_cv[t] = mV * rV;
    }
    __syncthreads();

    float rq[25]; float cQ = 0.f;
    #pragma unroll
    for (int p = 0; p < 25; ++p) { rq[p] = s_rq[p]; cQ += s_mq[p]; }

    if (stg) st4p(&PB[h][0][2 * eo], c0K, c0Q);
    // no fence: same-wave in-order LDS covers write->read; compiler inserts
    // counted lgkmcnt before first use of the reads.

    float sal[25];
    #pragma unroll
    for (int p = 0; p < 25; ++p) sal[p] = 0.f;
    float sumQ2 = 0.f, sumQB = 0.f;

    #pragma unroll 2
    for (int cc = 0; cc < 16; ++cc) {
        const int buf = cc & 1;
        if (stg && cc < 15) {
            st4p(&PB[h][buf ^ 1][2 * eo], nK, nQ);    // plane cc+1 (K,Q interleaved)
            nK = fK; nQ = fQ;
            if (cc < 13) {                            // K/Q plane cc+3
                fK = *(const u16x4*)(baseK + (size_t)(cc + 3) * PLANE + eo);
                fQ = *(const u16x4*)(baseQ + (size_t)(cc + 3) * PLANE + eo);
            } else if (cc == 13) {                    // tail: V0,V1
                fK = *(const u16x4*)(baseV + eo);
                fQ = *(const u16x4*)(baseV + (size_t)PLANE + eo);
            } else {                                  // cc == 14: V2,V3
                fK = *(const u16x4*)(baseV + 2 * (size_t)PLANE + eo);
                fQ = *(const u16x4*)(baseV + 3 * (size_t)PLANE + eo);
            }
        }
        const int ch = h * 16 + cc;
        const float* pb = &PB[h][buf][0];
        float kv[25];
        float qa0 = 0.f, qa1 = 0.f, qa2 = 0.f, qa3 = 0.f, qa4 = 0.f;
        #pragma unroll
        for (int kw = 0; kw < 5; ++kw) {
            const float2 t0 = *(const float2*)&pb[b2 + 2 * (0 * PW + kw)];
            const float2 t1 = *(const float2*)&pb[b2 + 2 * (1 * PW + kw)];
            const float2 t2 = *(const float2*)&pb[b2 + 2 * (2 * PW + kw)];
            const float2 t3 = *(const float2*)&pb[b2 + 2 * (3 * PW + kw)];
            const float2 t4 = *(const float2*)&pb[b2 + 2 * (4 * PW + kw)];
            kv[0 * 5 + kw] = t0.x; qa0 += rq[0 * 5 + kw] * t0.y;
            kv[1 * 5 + kw] = t1.x; qa1 += rq[1 * 5 + kw] * t1.y;
            kv[2 * 5 + kw] = t2.x; qa2 += rq[2 * 5 + kw] * t2.y;
            kv[3 * 5 + kw] = t3.x; qa3 += rq[3 * 5 + kw] * t3.y;
            kv[4 * 5 + kw] = t4.x; qa4 += rq[4 * 5 + kw] * t4.y;
        }
        const float qa = (qa0 + qa1) + (qa2 + qa3) + qa4;
        const float qk  = s_gw[32 + ch] * ((qa - cQ) * 0.04f) + s_gb[32 + ch];
        const float qk2 = qk * s_gw[ch];
        sumQ2 += qk2; sumQB += qk * s_gb[ch];
        #pragma unroll
        for (int p = 0; p < 25; ++p) sal[p] += qk2 * kv[p];
    }
    // exit: nK,nQ = V0,V1 ; fK,fQ = V2,V3

    // cross-wave exchange: write partials + stage V pair0, barrier
    #pragma unroll
    for (int p = 0; p < 25; ++p) ex[t][p] = sal[p];
    ex[t][25] = sumQ2; ex[t][26] = sumQB;
    if (stg) st4p(&PB[h][0][2 * eo], nK, nQ);   // pair0 = (V0,V1) -> buf0
    __syncthreads();
    const int par = t ^ 64;
    #pragma unroll
    for (int p = 0; p < 25; ++p) sal[p] += ex[par][p];
    sumQ2 += ex[par][25]; sumQB += ex[par][26];

    u16x4 vA0 = fK, vA1 = fQ;                    // pair1 = (V2,V3)
    u16x4 vB0{0,0,0,0}, vB1{0,0,0,0};
    if (stg) {                                   // pair2 = (V4,V5), post-barrier
        vB0 = *(const u16x4*)(baseV + 4 * (size_t)PLANE + eo);
        vB1 = *(const u16x4*)(baseV + 5 * (size_t)PLANE + eo);
    }

    #pragma unroll
    for (int p = 0; p < 25; ++p) sal[p] = s_rk[p] * sal[p] - s_ck[p] * sumQ2 + sumQB;

    const float scale = 0.17677669529663687f;  // 1/sqrt(32)
    float mmax = -3.4e38f;
    #pragma unroll
    for (int p = 0; p < 25; ++p) { sal[p] *= scale; mmax = fmaxf(mmax, sal[p]); }
    float ssum = 0.f;
    #pragma unroll
    for (int p = 0; p < 25; ++p) { sal[p] = __expf(sal[p] - mmax); ssum += sal[p]; }
    const float rs = 1.f / ssum;
    float cV2 = 0.f;
    #pragma unroll
    for (int p = 0; p < 25; ++p) {
        const float m = sal[p] * rs;
        sal[p] = m * s_rv[p];        // reuse sal as V-tap weights
        cV2 += m * s_cv[p];
    }

    // PV: 8 iterations, TWO V planes each (pair vp from buf vp&1); fence-free
    #pragma unroll 2
    for (int vp = 0; vp < 8; ++vp) {
        const int buf = vp & 1;
        if (stg && vp < 7) {
            st4p(&PB[h][buf ^ 1][2 * eo], vA0, vA1);   // pair vp+1
            vA0 = vB0; vA1 = vB1;
            if (vp < 5) {                              // pair vp+3 = planes 2vp+6, 2vp+7
                vB0 = *(const u16x4*)(baseV + (size_t)(2 * vp + 6) * PLANE + eo);
                vB1 = *(const u16x4*)(baseV + (size_t)(2 * vp + 7) * PLANE + eo);
            }
        }
        const int v0 = h * 16 + 2 * vp;
        const float* pb = &PB[h][buf][0];
        float l0 = 0.f, l1 = 0.f, l2 = 0.f, l3 = 0.f, l4 = 0.f;
        float g0 = 0.f, g1 = 0.f, g2 = 0.f, g3 = 0.f, g4 = 0.f;
        #pragma unroll
        for (int kw = 0; kw < 5; ++kw) {
            const float2 t0 = *(const float2*)&pb[b2 + 2 * (0 * PW + kw)];
            const float2 t1 = *(const float2*)&pb[b2 + 2 * (1 * PW + kw)];
            const float2 t2 = *(const float2*)&pb[b2 + 2 * (2 * PW + kw)];
            const float2 t3 = *(const float2*)&pb[b2 + 2 * (3 * PW + kw)];
            const float2 t4 = *(const float2*)&pb[b2 + 2 * (4 * PW + kw)];
            l0 += sal[0 * 5 + kw] * t0.x; g0 += sal[0 * 5 + kw] * t0.y;
            l1 += sal[1 * 5 + kw] * t1.x; g1 += sal[1 * 5 + kw] * t1.y;
            l2 += sal[2 * 5 + kw] * t2.x; g2 += sal[2 * 5 + kw] * t2.y;
            l3 += sal[3 * 5 + kw] * t3.x; g3 += sal[3 * 5 + kw] * t3.y;
            l4 += sal[4 * 5 + kw] * t4.x; g4 += sal[4 * 5 + kw] * t4.y;
        }
        const float aL = (l0 + l1) + (l2 + l3) + l4;
        const float aH = (g0 + g1) + (g2 + g3) + g4;
        const size_t ob = ((size_t)(b * 256 + n * 32 + v0) * 32 + (i0 + r)) * 32 + j;
        out[ob]        = s_gw[64 + v0] * aL + (s_gb[64 + v0] - s_gw[64 + v0] * cV2);
        out[ob + 1024] = s_gw[65 + v0] * aH + (s_gb[65 + v0] - s_gw[65 + v0] * cV2);
    }
}

extern "C" void kernel_launch(void* const* d_in, const int* in_sizes, int n_in,
                              void* d_out, int out_size, void* d_ws, size_t ws_size,
                              hipStream_t stream) {
    const float* x      = (const float*)d_in[0];
    const float* conv_w = (const float*)d_in[1];
    const float* conv_b = (const float*)d_in[2];
    const float* gn_w   = (const float*)d_in[3];
    const float* gn_b   = (const float*)d_in[4];
    float* out = (float*)d_out;

    // ws: attn bf16 padded | rowAgg f32 | xT bf16 | wbf bf16
    ushort_t* attn    = (ushort_t*)d_ws;                    // 8,847,360 ushorts
    float*    rowAgg  = (float*)(attn + 8847360);           // 61,440 floats
    ushort_t* xT      = (ushort_t*)(rowAgg + 61440);        // 2,097,152 ushorts
    ushort_t* wbf     = xT + 2097152;                       // 196,608 ushorts

    prep<<<608, 256, 0, stream>>>(x, conv_w, xT, wbf);
    conv_gemm<<<dim3(128, 12), 256, 0, stream>>>(wbf, xT, conv_b, attn, rowAgg);
    local_attn<<<1024, 128, 0, stream>>>(attn, rowAgg, gn_w, gn_b, out);
}